// Round 4
// baseline (343.357 us; speedup 1.0000x reference)
//
#include <hip/hip_runtime.h>
#include <hip/hip_bf16.h>
#include <math.h>

#define BB 4096
#define LL 16
#define SS 512
#define VV 512
#define II 512
#define HH 512

typedef __attribute__((ext_vector_type(4))) float f32x4;
typedef __attribute__((ext_vector_type(8))) short short8;

#define GLOBAL_AS __attribute__((address_space(1)))
#define LDS_AS __attribute__((address_space(3)))

__device__ __forceinline__ unsigned short f2bf(float f) {
    union { float f; unsigned u; } c; c.f = f;
    unsigned u = c.u + 0x7FFFu + ((c.u >> 16) & 1u);
    return (unsigned short)(u >> 16);
}
__device__ __forceinline__ float bf2f(unsigned short u) {
    union { unsigned u; float f; } c; c.u = ((unsigned)u) << 16;
    return c.f;
}
__device__ __forceinline__ float fast_tanh(float x) {
    return 1.f - 2.f / (__expf(2.f * x) + 1.f);
}

// ---------------------------------------------------------------------------
// MFMA GEMM, m97-style: BM=128, BN=NF*32, BK=64. 256 threads = 4 waves (2x2).
// Wave tile 64 x (NF*16). acc[4][NF]. LDS swizzled via pre-swizzled global src.
// MODE 0: float out. MODE 1: bf16 out. MODE 2: float out + o_ns row-15 copy.
// ---------------------------------------------------------------------------
template<int MODE, int NF>
__global__ __launch_bounds__(256) void gemm_mfma(
    const ushort* __restrict__ A, const ushort* __restrict__ Bt,
    const float* __restrict__ bias, void* __restrict__ C, float* __restrict__ C2,
    int ldc, int M, int N, int K) {
    constexpr int BN = NF * 32;
    __shared__ ushort Als[128 * 64];
    __shared__ ushort Bls[BN * 64];
    const int tid  = threadIdx.x;
    const int lane = tid & 63;
    const int w    = tid >> 6;
    const int wm   = w >> 1, wn = w & 1;
    const int brow = blockIdx.y * 128;
    const int bcol = blockIdx.x * BN;
    f32x4 acc[4][NF] = {};
    const int nkt = K >> 6;
    for (int kt = 0; kt < nkt; ++kt) {
        __syncthreads();
        #pragma unroll
        for (int i = 0; i < 4; ++i) {           // A: 1024 chunks of 16B
            int c0 = i * 256 + w * 64;
            int c  = c0 + lane;
            int row = c >> 3, sl = c & 7;
            const ushort* gp = A + (size_t)(brow + row) * K + kt * 64 + ((sl ^ (row & 7)) * 8);
            __builtin_amdgcn_global_load_lds((const GLOBAL_AS void*)gp,
                                             (LDS_AS void*)(Als + c0 * 8), 16, 0, 0);
        }
        #pragma unroll
        for (int i = 0; i < NF; ++i) {          // B: BN*8 chunks
            int c0 = i * 256 + w * 64;
            int c  = c0 + lane;
            int row = c >> 3, sl = c & 7;
            const ushort* gp = Bt + (size_t)(bcol + row) * K + kt * 64 + ((sl ^ (row & 7)) * 8);
            __builtin_amdgcn_global_load_lds((const GLOBAL_AS void*)gp,
                                             (LDS_AS void*)(Bls + c0 * 8), 16, 0, 0);
        }
        __syncthreads();
        const char* AlsB = (const char*)Als;
        const char* BlsB = (const char*)Bls;
        #pragma unroll
        for (int kh = 0; kh < 2; ++kh) {
            int ks = kh * 4 + (lane >> 4);
            short8 a[4], b[NF];
            #pragma unroll
            for (int m = 0; m < 4; ++m) {
                int row = wm * 64 + m * 16 + (lane & 15);
                a[m] = *(const short8*)(AlsB + (row * 8 + (ks ^ (row & 7))) * 16);
            }
            #pragma unroll
            for (int n = 0; n < NF; ++n) {
                int row = wn * (NF * 16) + n * 16 + (lane & 15);
                b[n] = *(const short8*)(BlsB + (row * 8 + (ks ^ (row & 7))) * 16);
            }
            #pragma unroll
            for (int m = 0; m < 4; ++m)
                #pragma unroll
                for (int n = 0; n < NF; ++n)
                    acc[m][n] = __builtin_amdgcn_mfma_f32_16x16x32_bf16(a[m], b[n], acc[m][n], 0, 0, 0);
        }
    }
    #pragma unroll
    for (int m = 0; m < 4; ++m)
        #pragma unroll
        for (int n = 0; n < NF; ++n)
            #pragma unroll
            for (int r = 0; r < 4; ++r) {
                int gm = brow + wm * 64 + m * 16 + (lane >> 4) * 4 + r;
                int gc = bcol + wn * (NF * 16) + n * 16 + (lane & 15);
                float v = acc[m][n][r] + bias[gc];
                if (MODE == 1) ((ushort*)C)[(size_t)gm * ldc + gc] = f2bf(v);
                else           ((float*)C)[(size_t)gm * ldc + gc] = v;
                if (MODE == 2) C2[((size_t)gm * 16 + 15) * 512 + gc] = v;
            }
}

// ---------------------------------------------------------------------------
// Fused score+softmax+d+shift v2: BM=64 (4 batches), 1024 blocks, 2 blocks/CU.
// A resident in 64KB LDS (bf16 swizzled). B (k^T) read DIRECTLY from global
// (L2-resident) into MFMA fragments with prefetch-1 -> no barriers in K loop.
// Wave grid 2x2, wave tile 32x32, acc[2][2].
// ---------------------------------------------------------------------------
__global__ __launch_bounds__(256) void score_fused(
    const float* __restrict__ ASf, const ushort* __restrict__ Bt,
    const float* __restrict__ Y, const float* __restrict__ vsum,
    float* __restrict__ o_ns, float* __restrict__ o_d, ushort* __restrict__ A7) {
    __shared__ ushort Als[64 * 512];   // 64 KB
    __shared__ float sred[2][64];
    __shared__ float s_lds[64];
    const int tid  = threadIdx.x;
    const int lane = tid & 63;
    const int w    = tid >> 6;
    const int wm   = w >> 1, wn = w & 1;
    const int brow = blockIdx.x * 64;
    const int bg0  = brow >> 4;
    char* AlsB = (char*)Als;

    // ---- Stage A: fp32 -> bf16 swizzled LDS; pass-through shifted o_ns ----
    #pragma unroll 4
    for (int i = 0; i < 16; ++i) {
        int c = i * 256 + tid;            // 16B-chunk id, 0..4095
        int row = c >> 6, slot = c & 63;
        const float* gp = ASf + (size_t)(brow + row) * 512 + slot * 8;
        float4 f0 = *(const float4*)gp;
        float4 f1 = *(const float4*)(gp + 4);
        if ((row & 15) != 0) {            // row l -> o_ns row l-1 (same batch)
            float* op = o_ns + (size_t)(brow + row - 1) * 512 + slot * 8;
            *(float4*)op = f0;
            *(float4*)(op + 4) = f1;
        }
        short8 pk;
        pk[0] = (short)f2bf(f0.x); pk[1] = (short)f2bf(f0.y);
        pk[2] = (short)f2bf(f0.z); pk[3] = (short)f2bf(f0.w);
        pk[4] = (short)f2bf(f1.x); pk[5] = (short)f2bf(f1.y);
        pk[6] = (short)f2bf(f1.z); pk[7] = (short)f2bf(f1.w);
        *(short8*)(AlsB + (row * 64 + (slot ^ (row & 7))) * 16) = pk;
    }
    __syncthreads();

    float rowsum[2][4] = {};
    for (int cb = 0; cb < 8; ++cb) {
        f32x4 acc[2][2] = {};
        const ushort* b0p = Bt + (size_t)(cb * 64 + wn * 32 + (lane & 15)) * 512 + (lane >> 4) * 8;
        const ushort* b1p = b0p + 16 * 512;
        short8 b0 = *(const short8*)b0p;
        short8 b1 = *(const short8*)b1p;
        #pragma unroll
        for (int kt = 0; kt < 16; ++kt) {
            short8 nb0 = b0, nb1 = b1;
            if (kt < 15) {
                nb0 = *(const short8*)(b0p + (kt + 1) * 32);
                nb1 = *(const short8*)(b1p + (kt + 1) * 32);
            }
            short8 a[2];
            #pragma unroll
            for (int m = 0; m < 2; ++m) {
                int row = wm * 32 + m * 16 + (lane & 15);
                int ps = (kt * 4 + (lane >> 4)) ^ (row & 7);
                a[m] = *(const short8*)(AlsB + (row * 64 + ps) * 16);
            }
            acc[0][0] = __builtin_amdgcn_mfma_f32_16x16x32_bf16(a[0], b0, acc[0][0], 0, 0, 0);
            acc[0][1] = __builtin_amdgcn_mfma_f32_16x16x32_bf16(a[0], b1, acc[0][1], 0, 0, 0);
            acc[1][0] = __builtin_amdgcn_mfma_f32_16x16x32_bf16(a[1], b0, acc[1][0], 0, 0, 0);
            acc[1][1] = __builtin_amdgcn_mfma_f32_16x16x32_bf16(a[1], b1, acc[1][1], 0, 0, 0);
            b0 = nb0; b1 = nb1;
        }
        // fused epilogue for this col-block
        #pragma unroll
        for (int m = 0; m < 2; ++m) {
            int yrow = bg0 + wm * 2 + m;
            #pragma unroll
            for (int n = 0; n < 2; ++n) {
                int gc = cb * 64 + wn * 32 + n * 16 + (lane & 15);
                float yv = Y[(size_t)yrow * 512 + gc];
                float vs = vsum[gc];
                #pragma unroll
                for (int r = 0; r < 4; ++r)
                    rowsum[m][r] += fast_tanh(acc[m][n][r] + yv) * vs;
            }
        }
    }
    // ---- reduce s across the 16 col-lanes ----
    #pragma unroll
    for (int m = 0; m < 2; ++m)
        #pragma unroll
        for (int r = 0; r < 4; ++r) {
            float v = rowsum[m][r];
            v += __shfl_xor(v, 1); v += __shfl_xor(v, 2);
            v += __shfl_xor(v, 4); v += __shfl_xor(v, 8);
            if ((lane & 15) == 0)
                sred[wn][wm * 32 + m * 16 + (lane >> 4) * 4 + r] = v;
        }
    __syncthreads();
    if (tid < 64) s_lds[tid] = sred[0][tid] + sred[1][tid];
    __syncthreads();

    // ---- softmax over L=16 + d from LDS; wave w handles local batch w ----
    {
        const int bl = w;
        const int bg = bg0 + bl;
        float mx = -1e30f;
        #pragma unroll
        for (int l = 0; l < LL; ++l) mx = fmaxf(mx, s_lds[bl * 16 + l]);
        float wgt[LL]; float sum = 0.f;
        #pragma unroll
        for (int l = 0; l < LL; ++l) { wgt[l] = __expf(s_lds[bl * 16 + l] - mx); sum += wgt[l]; }
        const float inv = 1.f / sum;
        float accv[8] = {};
        #pragma unroll
        for (int l = 0; l < LL; ++l) {
            int row = bl * 16 + l;
            short8 a = *(const short8*)(AlsB + (row * 64 + (lane ^ (l & 7))) * 16);
            #pragma unroll
            for (int j = 0; j < 8; ++j)
                accv[j] += wgt[l] * bf2f((unsigned short)a[j]);
        }
        float4 o0, o1;
        o0.x = accv[0] * inv; o0.y = accv[1] * inv; o0.z = accv[2] * inv; o0.w = accv[3] * inv;
        o1.x = accv[4] * inv; o1.y = accv[5] * inv; o1.z = accv[6] * inv; o1.w = accv[7] * inv;
        float* dp = o_d + (size_t)bg * 512 + lane * 8;
        *(float4*)dp = o0; *(float4*)(dp + 4) = o1;
        ushort4 u0, u1;
        u0.x = f2bf(o0.x); u0.y = f2bf(o0.y); u0.z = f2bf(o0.z); u0.w = f2bf(o0.w);
        u1.x = f2bf(o1.x); u1.y = f2bf(o1.y); u1.z = f2bf(o1.z); u1.w = f2bf(o1.w);
        ushort* ap = A7 + (size_t)bg * 1024 + 512 + lane * 8;
        *(ushort4*)ap = u0; *(ushort4*)(ap + 4) = u1;
    }
}

// transpose + cvt: dst[n][k] = (k<K0 ? srcA[k][n] : srcB[k-K0][n]) as bf16
__global__ void tr_cvt(const float* __restrict__ srcA, const float* __restrict__ srcB,
                       int K0, ushort* __restrict__ dst, int N, int K) {
    __shared__ float tile[32][33];
    int bn = blockIdx.x, bk = blockIdx.y;
    int tx = threadIdx.x, ty = threadIdx.y;  // 32 x 8
    #pragma unroll
    for (int j = 0; j < 4; ++j) {
        int k = bk * 32 + ty + j * 8;
        const float* s = (k < K0) ? (srcA + (size_t)k * N) : (srcB + (size_t)(k - K0) * N);
        tile[ty + j * 8][tx] = s[bn * 32 + tx];
    }
    __syncthreads();
    #pragma unroll
    for (int j = 0; j < 4; ++j) {
        int n = bn * 32 + ty + j * 8;
        dst[(size_t)n * K + bk * 32 + tx] = f2bf(tile[tx][ty + j * 8]);
    }
}

__global__ void cvt_strided(const float* __restrict__ src, ushort* __restrict__ dst,
                            int dstride) {
    int idx = blockIdx.x * 256 + threadIdx.x;
    int i4 = idx & 127, row = idx >> 7;
    float4 v = *(const float4*)(src + (size_t)row * 512 + i4 * 4);
    ushort4 o; o.x = f2bf(v.x); o.y = f2bf(v.y); o.z = f2bf(v.z); o.w = f2bf(v.w);
    *(ushort4*)(dst + (size_t)row * dstride + i4 * 4) = o;
}

__global__ void lstm_ew(const float4* __restrict__ g4, const float4* __restrict__ cc4,
                        float4* __restrict__ c4, float4* __restrict__ h4,
                        ushort* __restrict__ A4, ushort* __restrict__ A7) {
    int idx = blockIdx.x * 256 + threadIdx.x;   // BB*128
    int b = idx >> 7, q = idx & 127;
    const float4* g = g4 + (size_t)b * 512;
    float4 gi = g[q], gf = g[q + 128], gg = g[q + 256], go = g[q + 384];
    float4 cc = cc4[idx];
    float4 c, h;
    #pragma unroll
    for (int j = 0; j < 4; ++j) {
        float fi = ((const float*)&gi)[j], ff = ((const float*)&gf)[j];
        float fg = ((const float*)&gg)[j], fo = ((const float*)&go)[j];
        float si = 1.f / (1.f + __expf(-fi));
        float sf = 1.f / (1.f + __expf(-ff));
        float so = 1.f / (1.f + __expf(-fo));
        float cv = sf * ((const float*)&cc)[j] + si * tanhf(fg);
        ((float*)&c)[j] = cv;
        ((float*)&h)[j] = so * tanhf(cv);
    }
    c4[idx] = c; h4[idx] = h;
    ushort4 uc, uh;
    uc.x = f2bf(c.x); uc.y = f2bf(c.y); uc.z = f2bf(c.z); uc.w = f2bf(c.w);
    uh.x = f2bf(h.x); uh.y = f2bf(h.y); uh.z = f2bf(h.z); uh.w = f2bf(h.w);
    *(ushort4*)(A4 + (size_t)b * 1024 + q * 4) = uc;
    *(ushort4*)(A4 + (size_t)b * 1024 + 512 + q * 4) = uh;
    *(ushort4*)(A7 + (size_t)b * 1024 + q * 4) = uh;
}

__global__ void vsum_k(const float* __restrict__ Vm, float* __restrict__ out) {
    int v = threadIdx.x;
    float acc = 0.f;
    for (int s = 0; s < SS; ++s) acc += Vm[(size_t)s * VV + v];
    out[v] = acc;
}

extern "C" void kernel_launch(void* const* d_in, const int* in_sizes, int n_in,
                              void* d_out, int out_size, void* d_ws, size_t ws_size,
                              hipStream_t stream) {
    const float* inputs      = (const float*)d_in[0];
    const float* cell_c      = (const float*)d_in[1];
    const float* cell_h      = (const float*)d_in[2];
    const float* attns       = (const float*)d_in[3];
    const float* attn_states = (const float*)d_in[4];
    const float* W1          = (const float*)d_in[5];
    const float* b1          = (const float*)d_in[6];
    const float* Wx          = (const float*)d_in[7];
    const float* Wh          = (const float*)d_in[8];
    const float* b_lstm      = (const float*)d_in[9];
    const float* W3          = (const float*)d_in[10];
    const float* b3          = (const float*)d_in[11];
    const float* kmat        = (const float*)d_in[12];
    const float* vmat        = (const float*)d_in[13];
    const float* W2          = (const float*)d_in[14];
    const float* b2          = (const float*)d_in[15];

    float* o_out = (float*)d_out;
    float* o_c   = o_out + (size_t)BB * HH;
    float* o_h   = o_c   + (size_t)BB * HH;
    float* o_d   = o_h   + (size_t)BB * HH;
    float* o_ns  = o_d   + (size_t)BB * SS;

    float* ws_gates = (float*)d_ws;                          // B*4H
    float* ws_y     = ws_gates + (size_t)BB * 4 * HH;        // B*V
    float* ws_vsum  = ws_y + (size_t)BB * VV;                // V
    ushort* A1    = (ushort*)(ws_vsum + VV);                 // [B][1024]
    ushort* A2    = A1 + (size_t)BB * 1024;
    ushort* A4    = A2 + (size_t)BB * 1024;
    ushort* A7    = A4 + (size_t)BB * 1024;
    ushort* W1t   = A7 + (size_t)BB * 1024;                  // [512][1024]
    ushort* WxWht = W1t + (size_t)512 * 1024;                // [2048][1024]
    ushort* W3t   = WxWht + (size_t)2048 * 1024;             // [512][1024]
    ushort* W2t   = W3t + (size_t)512 * 1024;                // [512][1024]
    ushort* kTt   = W2t + (size_t)512 * 1024;                // [512][512]

    dim3 trb(32, 8);
    tr_cvt<<<dim3(512 / 32, 1024 / 32), trb, 0, stream>>>(W1, W1, 1024, W1t, 512, 1024);
    tr_cvt<<<dim3(2048 / 32, 1024 / 32), trb, 0, stream>>>(Wx, Wh, 512, WxWht, 2048, 1024);
    tr_cvt<<<dim3(512 / 32, 1024 / 32), trb, 0, stream>>>(W3, W3, 1024, W3t, 512, 1024);
    tr_cvt<<<dim3(512 / 32, 1024 / 32), trb, 0, stream>>>(W2, W2, 1024, W2t, 512, 1024);
    tr_cvt<<<dim3(512 / 32, 512 / 32), trb, 0, stream>>>(kmat, kmat, 512, kTt, 512, 512);
    vsum_k<<<1, 512, 0, stream>>>(vmat, ws_vsum);
    cvt_strided<<<BB * 128 / 256, 256, 0, stream>>>(inputs, A1, 1024);
    cvt_strided<<<BB * 128 / 256, 256, 0, stream>>>(attns, A1 + 512, 1024);
    cvt_strided<<<BB * 128 / 256, 256, 0, stream>>>(cell_h, A2 + 512, 1024);

    // 1. x = [inputs|attns] @ W1 + b1 -> bf16 into A2 left half
    gemm_mfma<1, 2><<<dim3(512 / 64, BB / 128), 256, 0, stream>>>(
        A1, W1t, b1, A2, nullptr, 1024, BB, 512, 1024);
    // 2. gates = [x|cell_h] @ [Wx;Wh] + b_lstm
    gemm_mfma<0, 4><<<dim3(2048 / 128, BB / 128), 256, 0, stream>>>(
        A2, WxWht, b_lstm, ws_gates, nullptr, 2048, BB, 2048, 1024);
    // 3. LSTM elementwise
    lstm_ew<<<BB * 128 / 256, 256, 0, stream>>>(
        (const float4*)ws_gates, (const float4*)cell_c,
        (float4*)o_c, (float4*)o_h, A4, A7);
    // 4. y = [c|h] @ W3 + b3
    gemm_mfma<0, 2><<<dim3(512 / 64, BB / 128), 256, 0, stream>>>(
        A4, W3t, b3, ws_y, nullptr, 512, BB, 512, 1024);
    // 5-6-8a. fused score + softmax + d + shifted o_ns rows 0..14
    score_fused<<<BB * LL / 64, 256, 0, stream>>>(
        attn_states, kTt, ws_y, ws_vsum, o_ns, o_d, A7);
    // 7+8b. output = [h|d] @ W2 + b2 (also writes o_ns row 15)
    gemm_mfma<2, 2><<<dim3(512 / 64, BB / 128), 256, 0, stream>>>(
        A7, W2t, b2, o_out, o_ns, 512, BB, 512, 1024);
}

// Round 5
// 318.719 us; speedup vs baseline: 1.0773x; 1.0773x over previous
//
#include <hip/hip_runtime.h>
#include <hip/hip_bf16.h>
#include <math.h>

#define BB 4096
#define LL 16
#define SS 512
#define VV 512
#define II 512
#define HH 512

typedef __attribute__((ext_vector_type(4))) float f32x4;
typedef __attribute__((ext_vector_type(8))) short short8;

#define GLOBAL_AS __attribute__((address_space(1)))
#define LDS_AS __attribute__((address_space(3)))

__device__ __forceinline__ unsigned short f2bf(float f) {
    union { float f; unsigned u; } c; c.f = f;
    unsigned u = c.u + 0x7FFFu + ((c.u >> 16) & 1u);
    return (unsigned short)(u >> 16);
}
__device__ __forceinline__ float bf2f(unsigned short u) {
    union { unsigned u; float f; } c; c.u = ((unsigned)u) << 16;
    return c.f;
}
__device__ __forceinline__ float fast_tanh(float x) {
    return 1.f - 2.f / (__expf(2.f * x) + 1.f);
}

// ---------------------------------------------------------------------------
// MFMA GEMM, m97-style: BM=128, BN=NF*32, BK=64. 256 threads = 4 waves (2x2).
// MODE 0: float out. MODE 1: bf16 out. MODE 2: float out + o_ns row-15 copy.
// ---------------------------------------------------------------------------
template<int MODE, int NF>
__global__ __launch_bounds__(256) void gemm_mfma(
    const ushort* __restrict__ A, const ushort* __restrict__ Bt,
    const float* __restrict__ bias, void* __restrict__ C, float* __restrict__ C2,
    int ldc, int M, int N, int K) {
    constexpr int BN = NF * 32;
    __shared__ ushort Als[128 * 64];
    __shared__ ushort Bls[BN * 64];
    const int tid  = threadIdx.x;
    const int lane = tid & 63;
    const int w    = tid >> 6;
    const int wm   = w >> 1, wn = w & 1;
    const int brow = blockIdx.y * 128;
    const int bcol = blockIdx.x * BN;
    f32x4 acc[4][NF] = {};
    const int nkt = K >> 6;
    for (int kt = 0; kt < nkt; ++kt) {
        __syncthreads();
        #pragma unroll
        for (int i = 0; i < 4; ++i) {           // A: 1024 chunks of 16B
            int c0 = i * 256 + w * 64;
            int c  = c0 + lane;
            int row = c >> 3, sl = c & 7;
            const ushort* gp = A + (size_t)(brow + row) * K + kt * 64 + ((sl ^ (row & 7)) * 8);
            __builtin_amdgcn_global_load_lds((const GLOBAL_AS void*)gp,
                                             (LDS_AS void*)(Als + c0 * 8), 16, 0, 0);
        }
        #pragma unroll
        for (int i = 0; i < NF; ++i) {          // B: BN*8 chunks
            int c0 = i * 256 + w * 64;
            int c  = c0 + lane;
            int row = c >> 3, sl = c & 7;
            const ushort* gp = Bt + (size_t)(bcol + row) * K + kt * 64 + ((sl ^ (row & 7)) * 8);
            __builtin_amdgcn_global_load_lds((const GLOBAL_AS void*)gp,
                                             (LDS_AS void*)(Bls + c0 * 8), 16, 0, 0);
        }
        __syncthreads();
        const char* AlsB = (const char*)Als;
        const char* BlsB = (const char*)Bls;
        #pragma unroll
        for (int kh = 0; kh < 2; ++kh) {
            int ks = kh * 4 + (lane >> 4);
            short8 a[4], b[NF];
            #pragma unroll
            for (int m = 0; m < 4; ++m) {
                int row = wm * 64 + m * 16 + (lane & 15);
                a[m] = *(const short8*)(AlsB + (row * 8 + (ks ^ (row & 7))) * 16);
            }
            #pragma unroll
            for (int n = 0; n < NF; ++n) {
                int row = wn * (NF * 16) + n * 16 + (lane & 15);
                b[n] = *(const short8*)(BlsB + (row * 8 + (ks ^ (row & 7))) * 16);
            }
            #pragma unroll
            for (int m = 0; m < 4; ++m)
                #pragma unroll
                for (int n = 0; n < NF; ++n)
                    acc[m][n] = __builtin_amdgcn_mfma_f32_16x16x32_bf16(a[m], b[n], acc[m][n], 0, 0, 0);
        }
    }
    #pragma unroll
    for (int m = 0; m < 4; ++m)
        #pragma unroll
        for (int n = 0; n < NF; ++n)
            #pragma unroll
            for (int r = 0; r < 4; ++r) {
                int gm = brow + wm * 64 + m * 16 + (lane >> 4) * 4 + r;
                int gc = bcol + wn * (NF * 16) + n * 16 + (lane & 15);
                float v = acc[m][n][r] + bias[gc];
                if (MODE == 1) ((ushort*)C)[(size_t)gm * ldc + gc] = f2bf(v);
                else           ((float*)C)[(size_t)gm * ldc + gc] = v;
                if (MODE == 2) C2[((size_t)gm * 16 + 15) * 512 + gc] = v;
            }
}

// ---------------------------------------------------------------------------
// Fused score+softmax+d+shift v3: staging & softmax/d phases identical to v2.
// Compute loop restructured: ks-outer / cb-inner, acc-resident across all 8
// col-blocks (acc[8][2][2]), depth-4 rotating B prefetch (8 loads in flight).
// ---------------------------------------------------------------------------
__global__ __launch_bounds__(256, 2) void score_fused(
    const float* __restrict__ ASf, const ushort* __restrict__ Bt,
    const float* __restrict__ Y, const float* __restrict__ vsum,
    float* __restrict__ o_ns, float* __restrict__ o_d, ushort* __restrict__ A7) {
    __shared__ ushort Als[64 * 512];   // 64 KB
    __shared__ float sred[2][64];
    __shared__ float s_lds[64];
    const int tid  = threadIdx.x;
    const int lane = tid & 63;
    const int w    = tid >> 6;
    const int wm   = w >> 1, wn = w & 1;
    const int brow = blockIdx.x * 64;
    const int bg0  = brow >> 4;
    char* AlsB = (char*)Als;

    // ---- Stage A: fp32 -> bf16 swizzled LDS; pass-through shifted o_ns ----
    #pragma unroll 4
    for (int i = 0; i < 16; ++i) {
        int c = i * 256 + tid;            // 16B-chunk id, 0..4095
        int row = c >> 6, slot = c & 63;
        const float* gp = ASf + (size_t)(brow + row) * 512 + slot * 8;
        float4 f0 = *(const float4*)gp;
        float4 f1 = *(const float4*)(gp + 4);
        if ((row & 15) != 0) {            // row l -> o_ns row l-1 (same batch)
            float* op = o_ns + (size_t)(brow + row - 1) * 512 + slot * 8;
            *(float4*)op = f0;
            *(float4*)(op + 4) = f1;
        }
        short8 pk;
        pk[0] = (short)f2bf(f0.x); pk[1] = (short)f2bf(f0.y);
        pk[2] = (short)f2bf(f0.z); pk[3] = (short)f2bf(f0.w);
        pk[4] = (short)f2bf(f1.x); pk[5] = (short)f2bf(f1.y);
        pk[6] = (short)f2bf(f1.z); pk[7] = (short)f2bf(f1.w);
        *(short8*)(AlsB + (row * 64 + (slot ^ (row & 7))) * 16) = pk;
    }
    __syncthreads();

    // ---- compute: 128 steps (ks 0..15 x cb 0..7), all-cb acc residency ----
    f32x4 acc[8][2][2] = {};
    const int arow0 = wm * 32 + (lane & 15);
    const int arow1 = arow0 + 16;
    const ushort* bbase = Bt + (size_t)(wn * 32 + (lane & 15)) * 512 + (lane >> 4) * 8;
    short8 bpre[4][2];
    #pragma unroll
    for (int s = 0; s < 4; ++s) {         // preload steps 0..3 (ks=0, cb=s)
        const ushort* np = bbase + (size_t)s * 64 * 512;
        bpre[s][0] = *(const short8*)np;
        bpre[s][1] = *(const short8*)(np + 16 * 512);
    }
    short8 a0, a1;
    #pragma unroll
    for (int step = 0; step < 128; ++step) {
        const int ks = step >> 3, cb = step & 7;
        if (cb == 0) {                    // new K-slice: fetch a-fragments
            int sl = ks * 4 + (lane >> 4);
            a0 = *(const short8*)(AlsB + (arow0 * 64 + (sl ^ (arow0 & 7))) * 16);
            a1 = *(const short8*)(AlsB + (arow1 * 64 + (sl ^ (arow1 & 7))) * 16);
        }
        short8 b0 = bpre[step & 3][0], b1 = bpre[step & 3][1];
        if (step < 124) {                 // refill slot 4 steps ahead
            int ns = step + 4;
            const ushort* np = bbase + (size_t)(ns & 7) * 64 * 512 + (ns >> 3) * 32;
            bpre[step & 3][0] = *(const short8*)np;
            bpre[step & 3][1] = *(const short8*)(np + 16 * 512);
        }
        acc[cb][0][0] = __builtin_amdgcn_mfma_f32_16x16x32_bf16(a0, b0, acc[cb][0][0], 0, 0, 0);
        acc[cb][0][1] = __builtin_amdgcn_mfma_f32_16x16x32_bf16(a0, b1, acc[cb][0][1], 0, 0, 0);
        acc[cb][1][0] = __builtin_amdgcn_mfma_f32_16x16x32_bf16(a1, b0, acc[cb][1][0], 0, 0, 0);
        acc[cb][1][1] = __builtin_amdgcn_mfma_f32_16x16x32_bf16(a1, b1, acc[cb][1][1], 0, 0, 0);
    }

    // ---- fused epilogue: tanh + vsum-weighted row sums over all cb ----
    float rowsum[2][4] = {};
    #pragma unroll
    for (int cb = 0; cb < 8; ++cb)
        #pragma unroll
        for (int m = 0; m < 2; ++m) {
            const int yrow = bg0 + wm * 2 + m;
            #pragma unroll
            for (int n = 0; n < 2; ++n) {
                int gc = cb * 64 + wn * 32 + n * 16 + (lane & 15);
                float yv = Y[(size_t)yrow * 512 + gc];
                float vs = vsum[gc];
                #pragma unroll
                for (int r = 0; r < 4; ++r)
                    rowsum[m][r] += fast_tanh(acc[cb][m][n][r] + yv) * vs;
            }
        }
    // ---- reduce s across the 16 col-lanes ----
    #pragma unroll
    for (int m = 0; m < 2; ++m)
        #pragma unroll
        for (int r = 0; r < 4; ++r) {
            float v = rowsum[m][r];
            v += __shfl_xor(v, 1); v += __shfl_xor(v, 2);
            v += __shfl_xor(v, 4); v += __shfl_xor(v, 8);
            if ((lane & 15) == 0)
                sred[wn][wm * 32 + m * 16 + (lane >> 4) * 4 + r] = v;
        }
    __syncthreads();
    if (tid < 64) s_lds[tid] = sred[0][tid] + sred[1][tid];
    __syncthreads();

    // ---- softmax over L=16 + d from LDS; wave w handles local batch w ----
    {
        const int bl = w;
        const int bg = bg0 + bl;
        float mx = -1e30f;
        #pragma unroll
        for (int l = 0; l < LL; ++l) mx = fmaxf(mx, s_lds[bl * 16 + l]);
        float wgt[LL]; float sum = 0.f;
        #pragma unroll
        for (int l = 0; l < LL; ++l) { wgt[l] = __expf(s_lds[bl * 16 + l] - mx); sum += wgt[l]; }
        const float inv = 1.f / sum;
        float accv[8] = {};
        #pragma unroll
        for (int l = 0; l < LL; ++l) {
            int row = bl * 16 + l;
            short8 a = *(const short8*)(AlsB + (row * 64 + (lane ^ (l & 7))) * 16);
            #pragma unroll
            for (int j = 0; j < 8; ++j)
                accv[j] += wgt[l] * bf2f((unsigned short)a[j]);
        }
        float4 o0, o1;
        o0.x = accv[0] * inv; o0.y = accv[1] * inv; o0.z = accv[2] * inv; o0.w = accv[3] * inv;
        o1.x = accv[4] * inv; o1.y = accv[5] * inv; o1.z = accv[6] * inv; o1.w = accv[7] * inv;
        float* dp = o_d + (size_t)bg * 512 + lane * 8;
        *(float4*)dp = o0; *(float4*)(dp + 4) = o1;
        ushort4 u0, u1;
        u0.x = f2bf(o0.x); u0.y = f2bf(o0.y); u0.z = f2bf(o0.z); u0.w = f2bf(o0.w);
        u1.x = f2bf(o1.x); u1.y = f2bf(o1.y); u1.z = f2bf(o1.z); u1.w = f2bf(o1.w);
        ushort* ap = A7 + (size_t)bg * 1024 + 512 + lane * 8;
        *(ushort4*)ap = u0; *(ushort4*)(ap + 4) = u1;
    }
}

// ---------------------------------------------------------------------------
// Merged weight transpose+cvt: all 5 weight matrices in one launch.
// ---------------------------------------------------------------------------
struct TrJob { const float* srcA; const float* srcB; int K0; ushort* dst; int N; int K; };
struct TrJobs { TrJob j[5]; };

__global__ void tr_cvt_all(TrJobs jobs) {
    TrJob jb = jobs.j[blockIdx.z];
    int bn = blockIdx.x, bk = blockIdx.y;
    if (bn * 32 >= jb.N || bk * 32 >= jb.K) return;
    __shared__ float tile[32][33];
    int tx = threadIdx.x, ty = threadIdx.y;  // 32 x 8
    #pragma unroll
    for (int j = 0; j < 4; ++j) {
        int k = bk * 32 + ty + j * 8;
        const float* s = (k < jb.K0) ? (jb.srcA + (size_t)k * jb.N)
                                     : (jb.srcB + (size_t)(k - jb.K0) * jb.N);
        tile[ty + j * 8][tx] = s[bn * 32 + tx];
    }
    __syncthreads();
    #pragma unroll
    for (int j = 0; j < 4; ++j) {
        int n = bn * 32 + ty + j * 8;
        jb.dst[(size_t)n * jb.K + bk * 32 + tx] = f2bf(tile[tx][ty + j * 8]);
    }
}

// Merged activation cvt (inputs/attns/cell_h -> bf16 halves of A1/A2)
struct CvJobs { const float* src[3]; ushort* dst[3]; };
__global__ void cvt_all(CvJobs jobs) {
    const float* src = jobs.src[blockIdx.y];
    ushort* dst = jobs.dst[blockIdx.y];
    int idx = blockIdx.x * 256 + threadIdx.x;
    int i4 = idx & 127, row = idx >> 7;
    float4 v = *(const float4*)(src + (size_t)row * 512 + i4 * 4);
    ushort4 o; o.x = f2bf(v.x); o.y = f2bf(v.y); o.z = f2bf(v.z); o.w = f2bf(v.w);
    *(ushort4*)(dst + (size_t)row * 1024 + i4 * 4) = o;
}

__global__ void lstm_ew(const float4* __restrict__ g4, const float4* __restrict__ cc4,
                        float4* __restrict__ c4, float4* __restrict__ h4,
                        ushort* __restrict__ A4, ushort* __restrict__ A7) {
    int idx = blockIdx.x * 256 + threadIdx.x;   // BB*128
    int b = idx >> 7, q = idx & 127;
    const float4* g = g4 + (size_t)b * 512;
    float4 gi = g[q], gf = g[q + 128], gg = g[q + 256], go = g[q + 384];
    float4 cc = cc4[idx];
    float4 c, h;
    #pragma unroll
    for (int j = 0; j < 4; ++j) {
        float fi = ((const float*)&gi)[j], ff = ((const float*)&gf)[j];
        float fg = ((const float*)&gg)[j], fo = ((const float*)&go)[j];
        float si = 1.f / (1.f + __expf(-fi));
        float sf = 1.f / (1.f + __expf(-ff));
        float so = 1.f / (1.f + __expf(-fo));
        float cv = sf * ((const float*)&cc)[j] + si * tanhf(fg);
        ((float*)&c)[j] = cv;
        ((float*)&h)[j] = so * tanhf(cv);
    }
    c4[idx] = c; h4[idx] = h;
    ushort4 uc, uh;
    uc.x = f2bf(c.x); uc.y = f2bf(c.y); uc.z = f2bf(c.z); uc.w = f2bf(c.w);
    uh.x = f2bf(h.x); uh.y = f2bf(h.y); uh.z = f2bf(h.z); uh.w = f2bf(h.w);
    *(ushort4*)(A4 + (size_t)b * 1024 + q * 4) = uc;
    *(ushort4*)(A4 + (size_t)b * 1024 + 512 + q * 4) = uh;
    *(ushort4*)(A7 + (size_t)b * 1024 + q * 4) = uh;
}

__global__ void vsum_k(const float* __restrict__ Vm, float* __restrict__ out) {
    // grid 16 x 256: block covers 32 cols, 8 s-strips per col
    __shared__ float red[8][32];
    int tc = threadIdx.x & 31, ts = threadIdx.x >> 5;
    int v = blockIdx.x * 32 + tc;
    float acc = 0.f;
    for (int s = ts; s < SS; s += 8) acc += Vm[(size_t)s * VV + v];
    red[ts][tc] = acc;
    __syncthreads();
    if (ts == 0) {
        float t = 0.f;
        #pragma unroll
        for (int j = 0; j < 8; ++j) t += red[j][tc];
        out[v] = t;
    }
}

extern "C" void kernel_launch(void* const* d_in, const int* in_sizes, int n_in,
                              void* d_out, int out_size, void* d_ws, size_t ws_size,
                              hipStream_t stream) {
    const float* inputs      = (const float*)d_in[0];
    const float* cell_c      = (const float*)d_in[1];
    const float* cell_h      = (const float*)d_in[2];
    const float* attns       = (const float*)d_in[3];
    const float* attn_states = (const float*)d_in[4];
    const float* W1          = (const float*)d_in[5];
    const float* b1          = (const float*)d_in[6];
    const float* Wx          = (const float*)d_in[7];
    const float* Wh          = (const float*)d_in[8];
    const float* b_lstm      = (const float*)d_in[9];
    const float* W3          = (const float*)d_in[10];
    const float* b3          = (const float*)d_in[11];
    const float* kmat        = (const float*)d_in[12];
    const float* vmat        = (const float*)d_in[13];
    const float* W2          = (const float*)d_in[14];
    const float* b2          = (const float*)d_in[15];

    float* o_out = (float*)d_out;
    float* o_c   = o_out + (size_t)BB * HH;
    float* o_h   = o_c   + (size_t)BB * HH;
    float* o_d   = o_h   + (size_t)BB * HH;
    float* o_ns  = o_d   + (size_t)BB * SS;

    float* ws_gates = (float*)d_ws;                          // B*4H
    float* ws_y     = ws_gates + (size_t)BB * 4 * HH;        // B*V
    float* ws_vsum  = ws_y + (size_t)BB * VV;                // V
    ushort* A1    = (ushort*)(ws_vsum + VV);                 // [B][1024]
    ushort* A2    = A1 + (size_t)BB * 1024;
    ushort* A4    = A2 + (size_t)BB * 1024;
    ushort* A7    = A4 + (size_t)BB * 1024;
    ushort* W1t   = A7 + (size_t)BB * 1024;                  // [512][1024]
    ushort* WxWht = W1t + (size_t)512 * 1024;                // [2048][1024]
    ushort* W3t   = WxWht + (size_t)2048 * 1024;             // [512][1024]
    ushort* W2t   = W3t + (size_t)512 * 1024;                // [512][1024]
    ushort* kTt   = W2t + (size_t)512 * 1024;                // [512][512]

    // merged weight prep (1 launch) + activation cvt (1 launch) + vsum
    TrJobs tj;
    tj.j[0] = {W1, W1, 1024, W1t, 512, 1024};
    tj.j[1] = {Wx, Wh, 512, WxWht, 2048, 1024};
    tj.j[2] = {W3, W3, 1024, W3t, 512, 1024};
    tj.j[3] = {W2, W2, 1024, W2t, 512, 1024};
    tj.j[4] = {kmat, kmat, 512, kTt, 512, 512};
    tr_cvt_all<<<dim3(64, 32, 5), dim3(32, 8), 0, stream>>>(tj);
    CvJobs cj;
    cj.src[0] = inputs; cj.dst[0] = A1;
    cj.src[1] = attns;  cj.dst[1] = A1 + 512;
    cj.src[2] = cell_h; cj.dst[2] = A2 + 512;
    cvt_all<<<dim3(BB * 128 / 256, 3), 256, 0, stream>>>(cj);
    vsum_k<<<16, 256, 0, stream>>>(vmat, ws_vsum);

    // 1. x = [inputs|attns] @ W1 + b1 -> bf16 into A2 left half
    gemm_mfma<1, 1><<<dim3(512 / 32, BB / 128), 256, 0, stream>>>(
        A1, W1t, b1, A2, nullptr, 1024, BB, 512, 1024);
    // 2. gates = [x|cell_h] @ [Wx;Wh] + b_lstm
    gemm_mfma<0, 4><<<dim3(2048 / 128, BB / 128), 256, 0, stream>>>(
        A2, WxWht, b_lstm, ws_gates, nullptr, 2048, BB, 2048, 1024);
    // 3. LSTM elementwise
    lstm_ew<<<BB * 128 / 256, 256, 0, stream>>>(
        (const float4*)ws_gates, (const float4*)cell_c,
        (float4*)o_c, (float4*)o_h, A4, A7);
    // 4. y = [c|h] @ W3 + b3
    gemm_mfma<0, 1><<<dim3(512 / 32, BB / 128), 256, 0, stream>>>(
        A4, W3t, b3, ws_y, nullptr, 512, BB, 512, 1024);
    // 5-6-8a. fused score + softmax + d + shifted o_ns rows 0..14
    score_fused<<<BB * LL / 64, 256, 0, stream>>>(
        attn_states, kTt, ws_y, ws_vsum, o_ns, o_d, A7);
    // 7+8b. output = [h|d] @ W2 + b2 (also writes o_ns row 15)
    gemm_mfma<2, 1><<<dim3(512 / 32, BB / 128), 256, 0, stream>>>(
        A7, W2t, b2, o_out, o_ns, 512, BB, 512, 1024);
}

// Round 6
// 312.975 us; speedup vs baseline: 1.0971x; 1.0184x over previous
//
#include <hip/hip_runtime.h>
#include <hip/hip_bf16.h>
#include <math.h>

#define BB 4096
#define LL 16
#define SS 512
#define VV 512
#define II 512
#define HH 512

typedef __attribute__((ext_vector_type(4))) float f32x4;
typedef __attribute__((ext_vector_type(8))) short short8;

#define GLOBAL_AS __attribute__((address_space(1)))
#define LDS_AS __attribute__((address_space(3)))

__device__ __forceinline__ unsigned short f2bf(float f) {
    union { float f; unsigned u; } c; c.f = f;
    unsigned u = c.u + 0x7FFFu + ((c.u >> 16) & 1u);
    return (unsigned short)(u >> 16);
}
__device__ __forceinline__ float bf2f(unsigned short u) {
    union { unsigned u; float f; } c; c.u = ((unsigned)u) << 16;
    return c.f;
}
__device__ __forceinline__ float fast_tanh(float x) {
    return 1.f - 2.f / (__expf(2.f * x) + 1.f);
}

// ---------------------------------------------------------------------------
// MFMA GEMM, m97-style: BM=128, BN=NF*32, BK=64. 256 threads = 4 waves (2x2).
// MODE 0: float out. MODE 1: bf16 out. MODE 2: float out + o_ns row-15 copy.
// ---------------------------------------------------------------------------
template<int MODE, int NF>
__global__ __launch_bounds__(256) void gemm_mfma(
    const ushort* __restrict__ A, const ushort* __restrict__ Bt,
    const float* __restrict__ bias, void* __restrict__ C, float* __restrict__ C2,
    int ldc, int M, int N, int K) {
    constexpr int BN = NF * 32;
    __shared__ ushort Als[128 * 64];
    __shared__ ushort Bls[BN * 64];
    const int tid  = threadIdx.x;
    const int lane = tid & 63;
    const int w    = tid >> 6;
    const int wm   = w >> 1, wn = w & 1;
    const int brow = blockIdx.y * 128;
    const int bcol = blockIdx.x * BN;
    f32x4 acc[4][NF] = {};
    const int nkt = K >> 6;
    for (int kt = 0; kt < nkt; ++kt) {
        __syncthreads();
        #pragma unroll
        for (int i = 0; i < 4; ++i) {           // A: 1024 chunks of 16B
            int c0 = i * 256 + w * 64;
            int c  = c0 + lane;
            int row = c >> 3, sl = c & 7;
            const ushort* gp = A + (size_t)(brow + row) * K + kt * 64 + ((sl ^ (row & 7)) * 8);
            __builtin_amdgcn_global_load_lds((const GLOBAL_AS void*)gp,
                                             (LDS_AS void*)(Als + c0 * 8), 16, 0, 0);
        }
        #pragma unroll
        for (int i = 0; i < NF; ++i) {          // B: BN*8 chunks
            int c0 = i * 256 + w * 64;
            int c  = c0 + lane;
            int row = c >> 3, sl = c & 7;
            const ushort* gp = Bt + (size_t)(bcol + row) * K + kt * 64 + ((sl ^ (row & 7)) * 8);
            __builtin_amdgcn_global_load_lds((const GLOBAL_AS void*)gp,
                                             (LDS_AS void*)(Bls + c0 * 8), 16, 0, 0);
        }
        __syncthreads();
        const char* AlsB = (const char*)Als;
        const char* BlsB = (const char*)Bls;
        #pragma unroll
        for (int kh = 0; kh < 2; ++kh) {
            int ks = kh * 4 + (lane >> 4);
            short8 a[4], b[NF];
            #pragma unroll
            for (int m = 0; m < 4; ++m) {
                int row = wm * 64 + m * 16 + (lane & 15);
                a[m] = *(const short8*)(AlsB + (row * 8 + (ks ^ (row & 7))) * 16);
            }
            #pragma unroll
            for (int n = 0; n < NF; ++n) {
                int row = wn * (NF * 16) + n * 16 + (lane & 15);
                b[n] = *(const short8*)(BlsB + (row * 8 + (ks ^ (row & 7))) * 16);
            }
            #pragma unroll
            for (int m = 0; m < 4; ++m)
                #pragma unroll
                for (int n = 0; n < NF; ++n)
                    acc[m][n] = __builtin_amdgcn_mfma_f32_16x16x32_bf16(a[m], b[n], acc[m][n], 0, 0, 0);
        }
    }
    #pragma unroll
    for (int m = 0; m < 4; ++m)
        #pragma unroll
        for (int n = 0; n < NF; ++n)
            #pragma unroll
            for (int r = 0; r < 4; ++r) {
                int gm = brow + wm * 64 + m * 16 + (lane >> 4) * 4 + r;
                int gc = bcol + wn * (NF * 16) + n * 16 + (lane & 15);
                float v = acc[m][n][r] + bias[gc];
                if (MODE == 1) ((ushort*)C)[(size_t)gm * ldc + gc] = f2bf(v);
                else           ((float*)C)[(size_t)gm * ldc + gc] = v;
                if (MODE == 2) C2[((size_t)gm * 16 + 15) * 512 + gc] = v;
            }
}

// ---------------------------------------------------------------------------
// score2: BM=32 (2 batches), 512 threads (8 waves), 2048 blocks, ~26KB LDS
// -> 2 blocks/CU = 16 waves/CU.
// Phase A: s[row] via MFMA; A K-tiles reg-staged (fp32->bf16) into padded
//          LDS (144B rows, conflict-light, no swizzle needed); B gathered
//          from L2 with static register double-buffer; T14 issue-early/
//          write-late staging. Wave w covers cols w*64..+63, all 32 rows.
// Phase B: softmax(L=16) + d + o_ns shift, streaming A from global (L2-hot).
// ---------------------------------------------------------------------------
__global__ __launch_bounds__(512) void score2(
    const float* __restrict__ ASf, const ushort* __restrict__ Bt,
    const float* __restrict__ Y, const float* __restrict__ vsum,
    float* __restrict__ o_ns, float* __restrict__ o_d, ushort* __restrict__ A7) {
    __shared__ ushort Atile[2][32 * 72];   // 72 ushorts = 144B padded rows
    __shared__ float sred[8][32];
    __shared__ float s_lds[32];
    __shared__ float dred[8][64][8];
    const int tid  = threadIdx.x;
    const int lane = tid & 63;
    const int w    = tid >> 6;
    const int l15  = lane & 15, l4 = lane >> 4;
    const int brow = blockIdx.x * 32;
    const int bg0  = brow >> 4;            // first of 2 batches in this block

    // ---- Phase A ----
    const int srow = tid >> 4, sc4 = tid & 15;  // staging: 32 rows x 16 chunks
    float4 sf;
    f32x4 acc[2][4] = {};
    const ushort* bcol = Bt + (size_t)(w * 64 + l15) * 512 + l4 * 8;
    short8 bc[4], bn[4];
    #pragma unroll
    for (int n = 0; n < 4; ++n) bc[n] = *(const short8*)(bcol + (size_t)n * 16 * 512);

    // prologue stage tile 0
    sf = *(const float4*)(ASf + (size_t)(brow + srow) * 512 + sc4 * 4);
    {
        ushort4 u; u.x = f2bf(sf.x); u.y = f2bf(sf.y); u.z = f2bf(sf.z); u.w = f2bf(sf.w);
        *(ushort4*)(&Atile[0][srow * 72 + sc4 * 4]) = u;
    }
    for (int t = 0; t < 8; ++t) {
        __syncthreads();
        if (t < 7)   // issue-early: next tile's global load
            sf = *(const float4*)(ASf + (size_t)(brow + srow) * 512 + (t + 1) * 64 + sc4 * 4);
        const ushort* At = &Atile[t & 1][0];
        #pragma unroll
        for (int s = 0; s < 2; ++s) {
            const int gs = 2 * t + s;
            short8 a0 = *(const short8*)(At + (size_t)l15 * 72 + (s * 4 + l4) * 8);
            short8 a1 = *(const short8*)(At + (size_t)(16 + l15) * 72 + (s * 4 + l4) * 8);
            if (gs < 15) {
                #pragma unroll
                for (int n = 0; n < 4; ++n)
                    bn[n] = *(const short8*)(bcol + (size_t)n * 16 * 512 + (gs + 1) * 32);
            }
            #pragma unroll
            for (int n = 0; n < 4; ++n) {
                acc[0][n] = __builtin_amdgcn_mfma_f32_16x16x32_bf16(a0, bc[n], acc[0][n], 0, 0, 0);
                acc[1][n] = __builtin_amdgcn_mfma_f32_16x16x32_bf16(a1, bc[n], acc[1][n], 0, 0, 0);
            }
            #pragma unroll
            for (int n = 0; n < 4; ++n) bc[n] = bn[n];
        }
        if (t < 7) {  // write-late: after this tile's MFMAs
            ushort4 u; u.x = f2bf(sf.x); u.y = f2bf(sf.y); u.z = f2bf(sf.z); u.w = f2bf(sf.w);
            *(ushort4*)(&Atile[(t + 1) & 1][srow * 72 + sc4 * 4]) = u;
        }
    }

    // tanh * vsum epilogue + 16-lane shuffle reduce
    float rowsum[2][4] = {};
    #pragma unroll
    for (int m = 0; m < 2; ++m)
        #pragma unroll
        for (int n = 0; n < 4; ++n) {
            int gc = w * 64 + n * 16 + l15;
            float yv = Y[(size_t)(bg0 + m) * 512 + gc];
            float vs = vsum[gc];
            #pragma unroll
            for (int r = 0; r < 4; ++r)
                rowsum[m][r] += fast_tanh(acc[m][n][r] + yv) * vs;
        }
    #pragma unroll
    for (int m = 0; m < 2; ++m)
        #pragma unroll
        for (int r = 0; r < 4; ++r) {
            float v = rowsum[m][r];
            v += __shfl_xor(v, 1); v += __shfl_xor(v, 2);
            v += __shfl_xor(v, 4); v += __shfl_xor(v, 8);
            if (l15 == 0) sred[w][m * 16 + l4 * 4 + r] = v;
        }
    __syncthreads();
    if (tid < 32) {
        float v = 0.f;
        #pragma unroll
        for (int q = 0; q < 8; ++q) v += sred[q][tid];
        s_lds[tid] = v;
    }
    __syncthreads();

    // ---- Phase B: softmax + d + o_ns shift (streams A from global) ----
    const int bl = w >> 2;                 // local batch 0/1
    const int rq = w & 3;                  // row-quarter
    const int bg = bg0 + bl;
    float mx = -1e30f;
    #pragma unroll
    for (int l = 0; l < LL; ++l) mx = fmaxf(mx, s_lds[bl * 16 + l]);
    float sum = 0.f;
    #pragma unroll
    for (int l = 0; l < LL; ++l) sum += __expf(s_lds[bl * 16 + l] - mx);
    const float inv = 1.f / sum;
    float w4[4];
    #pragma unroll
    for (int j = 0; j < 4; ++j) w4[j] = __expf(s_lds[bl * 16 + rq * 4 + j] - mx);

    float av[8] = {};
    #pragma unroll
    for (int j = 0; j < 4; ++j) {
        const int l = rq * 4 + j;
        const float* rp = ASf + ((size_t)bg * 16 + l) * 512 + lane * 8;
        float4 f0 = *(const float4*)rp;
        float4 f1 = *(const float4*)(rp + 4);
        if (l > 0) {
            float* op = o_ns + ((size_t)bg * 16 + l - 1) * 512 + lane * 8;
            *(float4*)op = f0;
            *(float4*)(op + 4) = f1;
        }
        av[0] += w4[j] * f0.x; av[1] += w4[j] * f0.y;
        av[2] += w4[j] * f0.z; av[3] += w4[j] * f0.w;
        av[4] += w4[j] * f1.x; av[5] += w4[j] * f1.y;
        av[6] += w4[j] * f1.z; av[7] += w4[j] * f1.w;
    }
    #pragma unroll
    for (int j = 0; j < 8; ++j) dred[w][lane][j] = av[j] * inv;
    __syncthreads();
    // combine 4 row-quarter partials; 512 threads x 2 cols
    {
        const int blc = tid >> 8;
        const int cc  = (tid & 255) * 2;
        float d0 = 0.f, d1 = 0.f;
        #pragma unroll
        for (int q = 0; q < 4; ++q) {
            d0 += dred[blc * 4 + q][cc >> 3][cc & 7];
            d1 += dred[blc * 4 + q][cc >> 3][(cc & 7) + 1];
        }
        const int bgc = bg0 + blc;
        float2 dv; dv.x = d0; dv.y = d1;
        *(float2*)(o_d + (size_t)bgc * 512 + cc) = dv;
        ushort2 uv; uv.x = f2bf(d0); uv.y = f2bf(d1);
        *(ushort2*)(A7 + (size_t)bgc * 1024 + 512 + cc) = uv;
    }
}

// ---------------------------------------------------------------------------
// Merged weight transpose+cvt: all 5 weight matrices in one launch.
// ---------------------------------------------------------------------------
struct TrJob { const float* srcA; const float* srcB; int K0; ushort* dst; int N; int K; };
struct TrJobs { TrJob j[5]; };

__global__ void tr_cvt_all(TrJobs jobs) {
    TrJob jb = jobs.j[blockIdx.z];
    int bn = blockIdx.x, bk = blockIdx.y;
    if (bn * 32 >= jb.N || bk * 32 >= jb.K) return;
    __shared__ float tile[32][33];
    int tx = threadIdx.x, ty = threadIdx.y;  // 32 x 8
    #pragma unroll
    for (int j = 0; j < 4; ++j) {
        int k = bk * 32 + ty + j * 8;
        const float* s = (k < jb.K0) ? (jb.srcA + (size_t)k * jb.N)
                                     : (jb.srcB + (size_t)(k - jb.K0) * jb.N);
        tile[ty + j * 8][tx] = s[bn * 32 + tx];
    }
    __syncthreads();
    #pragma unroll
    for (int j = 0; j < 4; ++j) {
        int n = bn * 32 + ty + j * 8;
        jb.dst[(size_t)n * jb.K + bk * 32 + tx] = f2bf(tile[tx][ty + j * 8]);
    }
}

// Merged activation cvt (inputs/attns/cell_h -> bf16 halves of A1/A2)
struct CvJobs { const float* src[3]; ushort* dst[3]; };
__global__ void cvt_all(CvJobs jobs) {
    const float* src = jobs.src[blockIdx.y];
    ushort* dst = jobs.dst[blockIdx.y];
    int idx = blockIdx.x * 256 + threadIdx.x;
    int i4 = idx & 127, row = idx >> 7;
    float4 v = *(const float4*)(src + (size_t)row * 512 + i4 * 4);
    ushort4 o; o.x = f2bf(v.x); o.y = f2bf(v.y); o.z = f2bf(v.z); o.w = f2bf(v.w);
    *(ushort4*)(dst + (size_t)row * 1024 + i4 * 4) = o;
}

__global__ void lstm_ew(const float4* __restrict__ g4, const float4* __restrict__ cc4,
                        float4* __restrict__ c4, float4* __restrict__ h4,
                        ushort* __restrict__ A4, ushort* __restrict__ A7) {
    int idx = blockIdx.x * 256 + threadIdx.x;   // BB*128
    int b = idx >> 7, q = idx & 127;
    const float4* g = g4 + (size_t)b * 512;
    float4 gi = g[q], gf = g[q + 128], gg = g[q + 256], go = g[q + 384];
    float4 cc = cc4[idx];
    float4 c, h;
    #pragma unroll
    for (int j = 0; j < 4; ++j) {
        float fi = ((const float*)&gi)[j], ff = ((const float*)&gf)[j];
        float fg = ((const float*)&gg)[j], fo = ((const float*)&go)[j];
        float si = 1.f / (1.f + __expf(-fi));
        float sf = 1.f / (1.f + __expf(-ff));
        float so = 1.f / (1.f + __expf(-fo));
        float cv = sf * ((const float*)&cc)[j] + si * tanhf(fg);
        ((float*)&c)[j] = cv;
        ((float*)&h)[j] = so * tanhf(cv);
    }
    c4[idx] = c; h4[idx] = h;
    ushort4 uc, uh;
    uc.x = f2bf(c.x); uc.y = f2bf(c.y); uc.z = f2bf(c.z); uc.w = f2bf(c.w);
    uh.x = f2bf(h.x); uh.y = f2bf(h.y); uh.z = f2bf(h.z); uh.w = f2bf(h.w);
    *(ushort4*)(A4 + (size_t)b * 1024 + q * 4) = uc;
    *(ushort4*)(A4 + (size_t)b * 1024 + 512 + q * 4) = uh;
    *(ushort4*)(A7 + (size_t)b * 1024 + q * 4) = uh;
}

__global__ void vsum_k(const float* __restrict__ Vm, float* __restrict__ out) {
    __shared__ float red[8][32];
    int tc = threadIdx.x & 31, ts = threadIdx.x >> 5;
    int v = blockIdx.x * 32 + tc;
    float acc = 0.f;
    for (int s = ts; s < SS; s += 8) acc += Vm[(size_t)s * VV + v];
    red[ts][tc] = acc;
    __syncthreads();
    if (ts == 0) {
        float t = 0.f;
        #pragma unroll
        for (int j = 0; j < 8; ++j) t += red[j][tc];
        out[v] = t;
    }
}

extern "C" void kernel_launch(void* const* d_in, const int* in_sizes, int n_in,
                              void* d_out, int out_size, void* d_ws, size_t ws_size,
                              hipStream_t stream) {
    const float* inputs      = (const float*)d_in[0];
    const float* cell_c      = (const float*)d_in[1];
    const float* cell_h      = (const float*)d_in[2];
    const float* attns       = (const float*)d_in[3];
    const float* attn_states = (const float*)d_in[4];
    const float* W1          = (const float*)d_in[5];
    const float* b1          = (const float*)d_in[6];
    const float* Wx          = (const float*)d_in[7];
    const float* Wh          = (const float*)d_in[8];
    const float* b_lstm      = (const float*)d_in[9];
    const float* W3          = (const float*)d_in[10];
    const float* b3          = (const float*)d_in[11];
    const float* kmat        = (const float*)d_in[12];
    const float* vmat        = (const float*)d_in[13];
    const float* W2          = (const float*)d_in[14];
    const float* b2          = (const float*)d_in[15];

    float* o_out = (float*)d_out;
    float* o_c   = o_out + (size_t)BB * HH;
    float* o_h   = o_c   + (size_t)BB * HH;
    float* o_d   = o_h   + (size_t)BB * HH;
    float* o_ns  = o_d   + (size_t)BB * SS;

    float* ws_gates = (float*)d_ws;                          // B*4H
    float* ws_y     = ws_gates + (size_t)BB * 4 * HH;        // B*V
    float* ws_vsum  = ws_y + (size_t)BB * VV;                // V
    ushort* A1    = (ushort*)(ws_vsum + VV);                 // [B][1024]
    ushort* A2    = A1 + (size_t)BB * 1024;
    ushort* A4    = A2 + (size_t)BB * 1024;
    ushort* A7    = A4 + (size_t)BB * 1024;
    ushort* W1t   = A7 + (size_t)BB * 1024;                  // [512][1024]
    ushort* WxWht = W1t + (size_t)512 * 1024;                // [2048][1024]
    ushort* W3t   = WxWht + (size_t)2048 * 1024;             // [512][1024]
    ushort* W2t   = W3t + (size_t)512 * 1024;                // [512][1024]
    ushort* kTt   = W2t + (size_t)512 * 1024;                // [512][512]

    TrJobs tj;
    tj.j[0] = {W1, W1, 1024, W1t, 512, 1024};
    tj.j[1] = {Wx, Wh, 512, WxWht, 2048, 1024};
    tj.j[2] = {W3, W3, 1024, W3t, 512, 1024};
    tj.j[3] = {W2, W2, 1024, W2t, 512, 1024};
    tj.j[4] = {kmat, kmat, 512, kTt, 512, 512};
    tr_cvt_all<<<dim3(64, 32, 5), dim3(32, 8), 0, stream>>>(tj);
    CvJobs cj;
    cj.src[0] = inputs; cj.dst[0] = A1;
    cj.src[1] = attns;  cj.dst[1] = A1 + 512;
    cj.src[2] = cell_h; cj.dst[2] = A2 + 512;
    cvt_all<<<dim3(BB * 128 / 256, 3), 256, 0, stream>>>(cj);
    vsum_k<<<16, 256, 0, stream>>>(vmat, ws_vsum);

    // 1. x = [inputs|attns] @ W1 + b1 -> bf16 into A2 left half
    gemm_mfma<1, 1><<<dim3(512 / 32, BB / 128), 256, 0, stream>>>(
        A1, W1t, b1, A2, nullptr, 1024, BB, 512, 1024);
    // 2. gates = [x|cell_h] @ [Wx;Wh] + b_lstm
    gemm_mfma<0, 4><<<dim3(2048 / 128, BB / 128), 256, 0, stream>>>(
        A2, WxWht, b_lstm, ws_gates, nullptr, 2048, BB, 2048, 1024);
    // 3. LSTM elementwise
    lstm_ew<<<BB * 128 / 256, 256, 0, stream>>>(
        (const float4*)ws_gates, (const float4*)cell_c,
        (float4*)o_c, (float4*)o_h, A4, A7);
    // 4. y = [c|h] @ W3 + b3
    gemm_mfma<0, 1><<<dim3(512 / 32, BB / 128), 256, 0, stream>>>(
        A4, W3t, b3, ws_y, nullptr, 512, BB, 512, 1024);
    // 5-6-8a. fused score + softmax + d + shifted o_ns rows 0..14
    score2<<<BB * LL / 32, 512, 0, stream>>>(
        attn_states, kTt, ws_y, ws_vsum, o_ns, o_d, A7);
    // 7+8b. output = [h|d] @ W2 + b2 (also writes o_ns row 15)
    gemm_mfma<2, 1><<<dim3(512 / 32, BB / 128), 256, 0, stream>>>(
        A7, W2t, b2, o_out, o_ns, 512, BB, 512, 1024);
}

// Round 7
// 296.091 us; speedup vs baseline: 1.1596x; 1.0570x over previous
//
#include <hip/hip_runtime.h>
#include <hip/hip_bf16.h>
#include <math.h>

#define BB 4096
#define LL 16
#define SS 512
#define VV 512
#define II 512
#define HH 512

typedef __attribute__((ext_vector_type(4))) float f32x4;
typedef __attribute__((ext_vector_type(8))) short short8;

#define GLOBAL_AS __attribute__((address_space(1)))
#define LDS_AS __attribute__((address_space(3)))

__device__ __forceinline__ unsigned short f2bf(float f) {
    union { float f; unsigned u; } c; c.f = f;
    unsigned u = c.u + 0x7FFFu + ((c.u >> 16) & 1u);
    return (unsigned short)(u >> 16);
}
__device__ __forceinline__ float bf2f(unsigned short u) {
    union { unsigned u; float f; } c; c.u = ((unsigned)u) << 16;
    return c.f;
}
__device__ __forceinline__ float fast_tanh(float x) {
    return 1.f - 2.f / (__expf(2.f * x) + 1.f);
}

// ---------------------------------------------------------------------------
// MFMA GEMM, m97-style: BM=128, BN=NF*32, BK=64. 256 threads = 4 waves (2x2).
// MODE 0: float out. MODE 1: bf16 out. MODE 2: float out + o_ns row-15 copy.
// ---------------------------------------------------------------------------
template<int MODE, int NF>
__global__ __launch_bounds__(256) void gemm_mfma(
    const ushort* __restrict__ A, const ushort* __restrict__ Bt,
    const float* __restrict__ bias, void* __restrict__ C, float* __restrict__ C2,
    int ldc, int M, int N, int K) {
    constexpr int BN = NF * 32;
    __shared__ ushort Als[128 * 64];
    __shared__ ushort Bls[BN * 64];
    const int tid  = threadIdx.x;
    const int lane = tid & 63;
    const int w    = tid >> 6;
    const int wm   = w >> 1, wn = w & 1;
    const int brow = blockIdx.y * 128;
    const int bcol = blockIdx.x * BN;
    f32x4 acc[4][NF] = {};
    const int nkt = K >> 6;
    for (int kt = 0; kt < nkt; ++kt) {
        __syncthreads();
        #pragma unroll
        for (int i = 0; i < 4; ++i) {           // A: 1024 chunks of 16B
            int c0 = i * 256 + w * 64;
            int c  = c0 + lane;
            int row = c >> 3, sl = c & 7;
            const ushort* gp = A + (size_t)(brow + row) * K + kt * 64 + ((sl ^ (row & 7)) * 8);
            __builtin_amdgcn_global_load_lds((const GLOBAL_AS void*)gp,
                                             (LDS_AS void*)(Als + c0 * 8), 16, 0, 0);
        }
        #pragma unroll
        for (int i = 0; i < NF; ++i) {          // B: BN*8 chunks
            int c0 = i * 256 + w * 64;
            int c  = c0 + lane;
            int row = c >> 3, sl = c & 7;
            const ushort* gp = Bt + (size_t)(bcol + row) * K + kt * 64 + ((sl ^ (row & 7)) * 8);
            __builtin_amdgcn_global_load_lds((const GLOBAL_AS void*)gp,
                                             (LDS_AS void*)(Bls + c0 * 8), 16, 0, 0);
        }
        __syncthreads();
        const char* AlsB = (const char*)Als;
        const char* BlsB = (const char*)Bls;
        #pragma unroll
        for (int kh = 0; kh < 2; ++kh) {
            int ks = kh * 4 + (lane >> 4);
            short8 a[4], b[NF];
            #pragma unroll
            for (int m = 0; m < 4; ++m) {
                int row = wm * 64 + m * 16 + (lane & 15);
                a[m] = *(const short8*)(AlsB + (row * 8 + (ks ^ (row & 7))) * 16);
            }
            #pragma unroll
            for (int n = 0; n < NF; ++n) {
                int row = wn * (NF * 16) + n * 16 + (lane & 15);
                b[n] = *(const short8*)(BlsB + (row * 8 + (ks ^ (row & 7))) * 16);
            }
            #pragma unroll
            for (int m = 0; m < 4; ++m)
                #pragma unroll
                for (int n = 0; n < NF; ++n)
                    acc[m][n] = __builtin_amdgcn_mfma_f32_16x16x32_bf16(a[m], b[n], acc[m][n], 0, 0, 0);
        }
    }
    #pragma unroll
    for (int m = 0; m < 4; ++m)
        #pragma unroll
        for (int n = 0; n < NF; ++n)
            #pragma unroll
            for (int r = 0; r < 4; ++r) {
                int gm = brow + wm * 64 + m * 16 + (lane >> 4) * 4 + r;
                int gc = bcol + wn * (NF * 16) + n * 16 + (lane & 15);
                float v = acc[m][n][r] + bias[gc];
                if (MODE == 1) ((ushort*)C)[(size_t)gm * ldc + gc] = f2bf(v);
                else           ((float*)C)[(size_t)gm * ldc + gc] = v;
                if (MODE == 2) C2[((size_t)gm * 16 + 15) * 512 + gc] = v;
            }
}

// ---------------------------------------------------------------------------
// Score GEMM v2 (R2 structure, BN=256): spart[cb][row] =
//   sum_{v in col-block cb} tanh((AS@K)[row,v] + Y[row>>4,v]) * vsum[v]
// A (attn_states fp32) reg-staged with fp32->bf16 cvt into swizzled LDS
// (R2-verified pattern); B (k^T bf16) via global_load_lds. Grid (2, 512).
// Only 2 col-blocks -> A fp32 refetch is 2x instead of 8x.
// ---------------------------------------------------------------------------
__global__ __launch_bounds__(256) void gemm_score(
    const float* __restrict__ ASf, const ushort* __restrict__ Bt,
    const float* __restrict__ Y, const float* __restrict__ vsum,
    float* __restrict__ spart) {
    __shared__ ushort Als[128 * 64];    // 16 KB
    __shared__ ushort Bls[256 * 64];    // 32 KB
    __shared__ float sred[2][128];
    const int tid  = threadIdx.x;
    const int lane = tid & 63;
    const int w    = tid >> 6;
    const int wm   = w >> 1, wn = w & 1;
    const int l15  = lane & 15, l4 = lane >> 4;
    const int brow = blockIdx.y * 128;
    const int bcol = blockIdx.x * 256;
    f32x4 acc[4][8] = {};
    for (int kt = 0; kt < 8; ++kt) {
        __syncthreads();
        // A: 1024 16B-chunks, 4/thread, fp32->bf16 cvt, swizzled-source write
        #pragma unroll
        for (int i = 0; i < 4; ++i) {
            int chunk = i * 256 + tid;
            int row = chunk >> 3, slot = chunk & 7;
            int gslot = slot ^ (row & 7);
            const float* gp = ASf + (size_t)(brow + row) * 512 + kt * 64 + gslot * 8;
            float4 f0 = *(const float4*)gp;
            float4 f1 = *(const float4*)(gp + 4);
            short8 pk;
            pk[0] = (short)f2bf(f0.x); pk[1] = (short)f2bf(f0.y);
            pk[2] = (short)f2bf(f0.z); pk[3] = (short)f2bf(f0.w);
            pk[4] = (short)f2bf(f1.x); pk[5] = (short)f2bf(f1.y);
            pk[6] = (short)f2bf(f1.z); pk[7] = (short)f2bf(f1.w);
            *(short8*)((char*)Als + chunk * 16) = pk;
        }
        // B: 2048 chunks via global_load_lds (swizzled global source)
        #pragma unroll
        for (int i = 0; i < 8; ++i) {
            int c0 = i * 256 + w * 64;
            int c  = c0 + lane;
            int row = c >> 3, sl = c & 7;
            const ushort* gp = Bt + (size_t)(bcol + row) * 512 + kt * 64 + ((sl ^ (row & 7)) * 8);
            __builtin_amdgcn_global_load_lds((const GLOBAL_AS void*)gp,
                                             (LDS_AS void*)(Bls + c0 * 8), 16, 0, 0);
        }
        __syncthreads();
        const char* AlsB = (const char*)Als;
        const char* BlsB = (const char*)Bls;
        #pragma unroll
        for (int kh = 0; kh < 2; ++kh) {
            int ks = kh * 4 + l4;
            short8 a[4];
            #pragma unroll
            for (int m = 0; m < 4; ++m) {
                int row = wm * 64 + m * 16 + l15;
                a[m] = *(const short8*)(AlsB + (row * 8 + (ks ^ (row & 7))) * 16);
            }
            #pragma unroll
            for (int n = 0; n < 8; ++n) {
                int rowb = wn * 128 + n * 16 + l15;
                short8 b = *(const short8*)(BlsB + (rowb * 8 + (ks ^ (rowb & 7))) * 16);
                #pragma unroll
                for (int m = 0; m < 4; ++m)
                    acc[m][n] = __builtin_amdgcn_mfma_f32_16x16x32_bf16(a[m], b, acc[m][n], 0, 0, 0);
            }
        }
    }
    // fused epilogue: tanh + vsum-weighted row reduction
    float part[4][4] = {};
    #pragma unroll
    for (int m = 0; m < 4; ++m) {
        int yb = (brow >> 4) + wm * 4 + m;
        #pragma unroll
        for (int n = 0; n < 8; ++n) {
            int gc = bcol + wn * 128 + n * 16 + l15;
            float yv = Y[(size_t)yb * 512 + gc];
            float vs = vsum[gc];
            #pragma unroll
            for (int r = 0; r < 4; ++r)
                part[m][r] += fast_tanh(acc[m][n][r] + yv) * vs;
        }
    }
    #pragma unroll
    for (int m = 0; m < 4; ++m)
        #pragma unroll
        for (int r = 0; r < 4; ++r) {
            float v = part[m][r];
            v += __shfl_xor(v, 1); v += __shfl_xor(v, 2);
            v += __shfl_xor(v, 4); v += __shfl_xor(v, 8);
            if (l15 == 0)
                sred[wn][wm * 64 + m * 16 + l4 * 4 + r] = v;
        }
    __syncthreads();
    if (tid < 128)
        spart[(size_t)blockIdx.x * (BB * LL) + brow + tid] = sred[0][tid] + sred[1][tid];
}

// ---------------------------------------------------------------------------
// softmax_d3: one block per batch. Reduces spart (2 partials), softmax over
// L=16, computes d = a @ AS, writes o_d (fp32) + A7 right half (bf16), and
// streams the o_ns shifted rows 0..14 in the same pass over AS.
// ---------------------------------------------------------------------------
__global__ __launch_bounds__(256) void softmax_d3(
    const float* __restrict__ spart, const float* __restrict__ ASf,
    float* __restrict__ o_ns, float* __restrict__ o_d, ushort* __restrict__ A7) {
    const int b = blockIdx.x, tid = threadIdx.x;
    __shared__ float s_l[LL];
    if (tid < LL)
        s_l[tid] = spart[(size_t)b * LL + tid] + spart[(size_t)BB * LL + b * LL + tid];
    __syncthreads();
    float mx = -1e30f;
    #pragma unroll
    for (int l = 0; l < LL; ++l) mx = fmaxf(mx, s_l[l]);
    float wgt[LL]; float sum = 0.f;
    #pragma unroll
    for (int l = 0; l < LL; ++l) { wgt[l] = __expf(s_l[l] - mx); sum += wgt[l]; }
    const float inv = 1.f / sum;
    const int c = tid * 2;
    float d0 = 0.f, d1 = 0.f;
    #pragma unroll
    for (int l = 0; l < LL; ++l) {
        float2 v = *(const float2*)(ASf + ((size_t)b * LL + l) * 512 + c);
        if (l >= 1)
            *(float2*)(o_ns + ((size_t)b * LL + l - 1) * 512 + c) = v;
        d0 += wgt[l] * v.x; d1 += wgt[l] * v.y;
    }
    d0 *= inv; d1 *= inv;
    float2 dv; dv.x = d0; dv.y = d1;
    *(float2*)(o_d + (size_t)b * 512 + c) = dv;
    ushort2 uv; uv.x = f2bf(d0); uv.y = f2bf(d1);
    *(ushort2*)(A7 + (size_t)b * 1024 + 512 + c) = uv;
}

// ---------------------------------------------------------------------------
// Merged weight transpose+cvt: all 5 weight matrices in one launch.
// ---------------------------------------------------------------------------
struct TrJob { const float* srcA; const float* srcB; int K0; ushort* dst; int N; int K; };
struct TrJobs { TrJob j[5]; };

__global__ void tr_cvt_all(TrJobs jobs) {
    TrJob jb = jobs.j[blockIdx.z];
    int bn = blockIdx.x, bk = blockIdx.y;
    if (bn * 32 >= jb.N || bk * 32 >= jb.K) return;
    __shared__ float tile[32][33];
    int tx = threadIdx.x, ty = threadIdx.y;  // 32 x 8
    #pragma unroll
    for (int j = 0; j < 4; ++j) {
        int k = bk * 32 + ty + j * 8;
        const float* s = (k < jb.K0) ? (jb.srcA + (size_t)k * jb.N)
                                     : (jb.srcB + (size_t)(k - jb.K0) * jb.N);
        tile[ty + j * 8][tx] = s[bn * 32 + tx];
    }
    __syncthreads();
    #pragma unroll
    for (int j = 0; j < 4; ++j) {
        int n = bn * 32 + ty + j * 8;
        jb.dst[(size_t)n * jb.K + bk * 32 + tx] = f2bf(tile[tx][ty + j * 8]);
    }
}

// Merged activation cvt (inputs/attns/cell_h -> bf16 halves of A1/A2)
struct CvJobs { const float* src[3]; ushort* dst[3]; };
__global__ void cvt_all(CvJobs jobs) {
    const float* src = jobs.src[blockIdx.y];
    ushort* dst = jobs.dst[blockIdx.y];
    int idx = blockIdx.x * 256 + threadIdx.x;
    int i4 = idx & 127, row = idx >> 7;
    float4 v = *(const float4*)(src + (size_t)row * 512 + i4 * 4);
    ushort4 o; o.x = f2bf(v.x); o.y = f2bf(v.y); o.z = f2bf(v.z); o.w = f2bf(v.w);
    *(ushort4*)(dst + (size_t)row * 1024 + i4 * 4) = o;
}

__global__ void lstm_ew(const float4* __restrict__ g4, const float4* __restrict__ cc4,
                        float4* __restrict__ c4, float4* __restrict__ h4,
                        ushort* __restrict__ A4, ushort* __restrict__ A7) {
    int idx = blockIdx.x * 256 + threadIdx.x;   // BB*128
    int b = idx >> 7, q = idx & 127;
    const float4* g = g4 + (size_t)b * 512;
    float4 gi = g[q], gf = g[q + 128], gg = g[q + 256], go = g[q + 384];
    float4 cc = cc4[idx];
    float4 c, h;
    #pragma unroll
    for (int j = 0; j < 4; ++j) {
        float fi = ((const float*)&gi)[j], ff = ((const float*)&gf)[j];
        float fg = ((const float*)&gg)[j], fo = ((const float*)&go)[j];
        float si = 1.f / (1.f + __expf(-fi));
        float sf = 1.f / (1.f + __expf(-ff));
        float so = 1.f / (1.f + __expf(-fo));
        float cv = sf * ((const float*)&cc)[j] + si * tanhf(fg);
        ((float*)&c)[j] = cv;
        ((float*)&h)[j] = so * tanhf(cv);
    }
    c4[idx] = c; h4[idx] = h;
    ushort4 uc, uh;
    uc.x = f2bf(c.x); uc.y = f2bf(c.y); uc.z = f2bf(c.z); uc.w = f2bf(c.w);
    uh.x = f2bf(h.x); uh.y = f2bf(h.y); uh.z = f2bf(h.z); uh.w = f2bf(h.w);
    *(ushort4*)(A4 + (size_t)b * 1024 + q * 4) = uc;
    *(ushort4*)(A4 + (size_t)b * 1024 + 512 + q * 4) = uh;
    *(ushort4*)(A7 + (size_t)b * 1024 + q * 4) = uh;
}

__global__ void vsum_k(const float* __restrict__ Vm, float* __restrict__ out) {
    __shared__ float red[8][32];
    int tc = threadIdx.x & 31, ts = threadIdx.x >> 5;
    int v = blockIdx.x * 32 + tc;
    float acc = 0.f;
    for (int s = ts; s < SS; s += 8) acc += Vm[(size_t)s * VV + v];
    red[ts][tc] = acc;
    __syncthreads();
    if (ts == 0) {
        float t = 0.f;
        #pragma unroll
        for (int j = 0; j < 8; ++j) t += red[j][tc];
        out[v] = t;
    }
}

extern "C" void kernel_launch(void* const* d_in, const int* in_sizes, int n_in,
                              void* d_out, int out_size, void* d_ws, size_t ws_size,
                              hipStream_t stream) {
    const float* inputs      = (const float*)d_in[0];
    const float* cell_c      = (const float*)d_in[1];
    const float* cell_h      = (const float*)d_in[2];
    const float* attns       = (const float*)d_in[3];
    const float* attn_states = (const float*)d_in[4];
    const float* W1          = (const float*)d_in[5];
    const float* b1          = (const float*)d_in[6];
    const float* Wx          = (const float*)d_in[7];
    const float* Wh          = (const float*)d_in[8];
    const float* b_lstm      = (const float*)d_in[9];
    const float* W3          = (const float*)d_in[10];
    const float* b3          = (const float*)d_in[11];
    const float* kmat        = (const float*)d_in[12];
    const float* vmat        = (const float*)d_in[13];
    const float* W2          = (const float*)d_in[14];
    const float* b2          = (const float*)d_in[15];

    float* o_out = (float*)d_out;
    float* o_c   = o_out + (size_t)BB * HH;
    float* o_h   = o_c   + (size_t)BB * HH;
    float* o_d   = o_h   + (size_t)BB * HH;
    float* o_ns  = o_d   + (size_t)BB * SS;

    float* ws_gates = (float*)d_ws;                          // B*4H
    float* ws_y     = ws_gates + (size_t)BB * 4 * HH;        // B*V
    float* ws_vsum  = ws_y + (size_t)BB * VV;                // V
    float* ws_spart = ws_vsum + VV;                          // 2*B*L
    ushort* A1    = (ushort*)(ws_spart + (size_t)2 * BB * LL);
    ushort* A2    = A1 + (size_t)BB * 1024;
    ushort* A4    = A2 + (size_t)BB * 1024;
    ushort* A7    = A4 + (size_t)BB * 1024;
    ushort* W1t   = A7 + (size_t)BB * 1024;                  // [512][1024]
    ushort* WxWht = W1t + (size_t)512 * 1024;                // [2048][1024]
    ushort* W3t   = WxWht + (size_t)2048 * 1024;             // [512][1024]
    ushort* W2t   = W3t + (size_t)512 * 1024;                // [512][1024]
    ushort* kTt   = W2t + (size_t)512 * 1024;                // [512][512]

    TrJobs tj;
    tj.j[0] = {W1, W1, 1024, W1t, 512, 1024};
    tj.j[1] = {Wx, Wh, 512, WxWht, 2048, 1024};
    tj.j[2] = {W3, W3, 1024, W3t, 512, 1024};
    tj.j[3] = {W2, W2, 1024, W2t, 512, 1024};
    tj.j[4] = {kmat, kmat, 512, kTt, 512, 512};
    tr_cvt_all<<<dim3(64, 32, 5), dim3(32, 8), 0, stream>>>(tj);
    CvJobs cj;
    cj.src[0] = inputs; cj.dst[0] = A1;
    cj.src[1] = attns;  cj.dst[1] = A1 + 512;
    cj.src[2] = cell_h; cj.dst[2] = A2 + 512;
    cvt_all<<<dim3(BB * 128 / 256, 3), 256, 0, stream>>>(cj);
    vsum_k<<<16, 256, 0, stream>>>(vmat, ws_vsum);

    // 1. x = [inputs|attns] @ W1 + b1 -> bf16 into A2 left half
    gemm_mfma<1, 1><<<dim3(512 / 32, BB / 128), 256, 0, stream>>>(
        A1, W1t, b1, A2, nullptr, 1024, BB, 512, 1024);
    // 2. gates = [x|cell_h] @ [Wx;Wh] + b_lstm
    gemm_mfma<0, 4><<<dim3(2048 / 128, BB / 128), 256, 0, stream>>>(
        A2, WxWht, b_lstm, ws_gates, nullptr, 2048, BB, 2048, 1024);
    // 3. LSTM elementwise
    lstm_ew<<<BB * 128 / 256, 256, 0, stream>>>(
        (const float4*)ws_gates, (const float4*)cell_c,
        (float4*)o_c, (float4*)o_h, A4, A7);
    // 4. y = [c|h] @ W3 + b3
    gemm_mfma<0, 1><<<dim3(512 / 32, BB / 128), 256, 0, stream>>>(
        A4, W3t, b3, ws_y, nullptr, 512, BB, 512, 1024);
    // 5. score partials (streaming m97-style, BN=256)
    gemm_score<<<dim3(2, 512), 256, 0, stream>>>(
        attn_states, kTt, ws_y, ws_vsum, ws_spart);
    // 6. reduce + softmax + d + o_ns rows 0..14 (one streaming pass)
    softmax_d3<<<BB, 256, 0, stream>>>(
        ws_spart, attn_states, o_ns, o_d, A7);
    // 7+8b. output = [h|d] @ W2 + b2 (also writes o_ns row 15)
    gemm_mfma<2, 1><<<dim3(512 / 32, BB / 128), 256, 0, stream>>>(
        A7, W2t, b2, o_out, o_ns, 512, BB, 512, 1024);
}

// Round 8
// 247.824 us; speedup vs baseline: 1.3855x; 1.1948x over previous
//
#include <hip/hip_runtime.h>
#include <hip/hip_bf16.h>
#include <math.h>

#define BB 4096
#define LL 16
#define SS 512
#define VV 512
#define II 512
#define HH 512

typedef __attribute__((ext_vector_type(4))) float f32x4;
typedef __attribute__((ext_vector_type(8))) short short8;

#define GLOBAL_AS __attribute__((address_space(1)))
#define LDS_AS __attribute__((address_space(3)))

__device__ __forceinline__ unsigned short f2bf(float f) {
    union { float f; unsigned u; } c; c.f = f;
    unsigned u = c.u + 0x7FFFu + ((c.u >> 16) & 1u);
    return (unsigned short)(u >> 16);
}
__device__ __forceinline__ float bf2f(unsigned short u) {
    union { unsigned u; float f; } c; c.u = ((unsigned)u) << 16;
    return c.f;
}
__device__ __forceinline__ float fast_tanh(float x) {
    return 1.f - 2.f / (__expf(2.f * x) + 1.f);
}

// ---------------------------------------------------------------------------
// MFMA GEMM, m97-style: BM=128, BN=NF*32, BK=64. 256 threads = 4 waves (2x2).
// MODE 0: float out. MODE 1: bf16 out. MODE 2: float out + o_ns row-15 copy.
// ---------------------------------------------------------------------------
template<int MODE, int NF>
__global__ __launch_bounds__(256) void gemm_mfma(
    const ushort* __restrict__ A, const ushort* __restrict__ Bt,
    const float* __restrict__ bias, void* __restrict__ C, float* __restrict__ C2,
    int ldc, int M, int N, int K) {
    constexpr int BN = NF * 32;
    __shared__ ushort Als[128 * 64];
    __shared__ ushort Bls[BN * 64];
    const int tid  = threadIdx.x;
    const int lane = tid & 63;
    const int w    = tid >> 6;
    const int wm   = w >> 1, wn = w & 1;
    const int brow = blockIdx.y * 128;
    const int bcol = blockIdx.x * BN;
    f32x4 acc[4][NF] = {};
    const int nkt = K >> 6;
    for (int kt = 0; kt < nkt; ++kt) {
        __syncthreads();
        #pragma unroll
        for (int i = 0; i < 4; ++i) {           // A: 1024 chunks of 16B
            int c0 = i * 256 + w * 64;
            int c  = c0 + lane;
            int row = c >> 3, sl = c & 7;
            const ushort* gp = A + (size_t)(brow + row) * K + kt * 64 + ((sl ^ (row & 7)) * 8);
            __builtin_amdgcn_global_load_lds((const GLOBAL_AS void*)gp,
                                             (LDS_AS void*)(Als + c0 * 8), 16, 0, 0);
        }
        #pragma unroll
        for (int i = 0; i < NF; ++i) {          // B: BN*8 chunks
            int c0 = i * 256 + w * 64;
            int c  = c0 + lane;
            int row = c >> 3, sl = c & 7;
            const ushort* gp = Bt + (size_t)(bcol + row) * K + kt * 64 + ((sl ^ (row & 7)) * 8);
            __builtin_amdgcn_global_load_lds((const GLOBAL_AS void*)gp,
                                             (LDS_AS void*)(Bls + c0 * 8), 16, 0, 0);
        }
        __syncthreads();
        const char* AlsB = (const char*)Als;
        const char* BlsB = (const char*)Bls;
        #pragma unroll
        for (int kh = 0; kh < 2; ++kh) {
            int ks = kh * 4 + (lane >> 4);
            short8 a[4], b[NF];
            #pragma unroll
            for (int m = 0; m < 4; ++m) {
                int row = wm * 64 + m * 16 + (lane & 15);
                a[m] = *(const short8*)(AlsB + (row * 8 + (ks ^ (row & 7))) * 16);
            }
            #pragma unroll
            for (int n = 0; n < NF; ++n) {
                int row = wn * (NF * 16) + n * 16 + (lane & 15);
                b[n] = *(const short8*)(BlsB + (row * 8 + (ks ^ (row & 7))) * 16);
            }
            #pragma unroll
            for (int m = 0; m < 4; ++m)
                #pragma unroll
                for (int n = 0; n < NF; ++n)
                    acc[m][n] = __builtin_amdgcn_mfma_f32_16x16x32_bf16(a[m], b[n], acc[m][n], 0, 0, 0);
        }
    }
    #pragma unroll
    for (int m = 0; m < 4; ++m)
        #pragma unroll
        for (int n = 0; n < NF; ++n)
            #pragma unroll
            for (int r = 0; r < 4; ++r) {
                int gm = brow + wm * 64 + m * 16 + (lane >> 4) * 4 + r;
                int gc = bcol + wn * (NF * 16) + n * 16 + (lane & 15);
                float v = acc[m][n][r] + bias[gc];
                if (MODE == 1) ((ushort*)C)[(size_t)gm * ldc + gc] = f2bf(v);
                else           ((float*)C)[(size_t)gm * ldc + gc] = v;
                if (MODE == 2) C2[((size_t)gm * 16 + 15) * 512 + gc] = v;
            }
}

// ---------------------------------------------------------------------------
// Score GEMM v4: same R2/R7-verified streaming structure, but 512 threads
// (8 waves, wave grid 2x4, wave tile 64x64, acc[4][4]) to halve per-wave
// register footprint and restore occupancy. BM=128, BN=256, grid (2, 512).
// ---------------------------------------------------------------------------
__global__ __launch_bounds__(512) void gemm_score(
    const float* __restrict__ ASf, const ushort* __restrict__ Bt,
    const float* __restrict__ Y, const float* __restrict__ vsum,
    float* __restrict__ spart) {
    __shared__ ushort Als[128 * 64];    // 16 KB
    __shared__ ushort Bls[256 * 64];    // 32 KB
    __shared__ float sred[4][128];
    const int tid  = threadIdx.x;
    const int lane = tid & 63;
    const int w    = tid >> 6;          // 0..7
    const int wm   = w >> 2, wn = w & 3;
    const int l15  = lane & 15, l4 = lane >> 4;
    const int brow = blockIdx.y * 128;
    const int bcol = blockIdx.x * 256;
    f32x4 acc[4][4] = {};
    for (int kt = 0; kt < 8; ++kt) {
        __syncthreads();
        // A: 1024 16B-chunks, 2/thread, fp32->bf16 cvt, swizzled-source write
        #pragma unroll
        for (int i = 0; i < 2; ++i) {
            int chunk = i * 512 + tid;
            int row = chunk >> 3, slot = chunk & 7;
            int gslot = slot ^ (row & 7);
            const float* gp = ASf + (size_t)(brow + row) * 512 + kt * 64 + gslot * 8;
            float4 f0 = *(const float4*)gp;
            float4 f1 = *(const float4*)(gp + 4);
            short8 pk;
            pk[0] = (short)f2bf(f0.x); pk[1] = (short)f2bf(f0.y);
            pk[2] = (short)f2bf(f0.z); pk[3] = (short)f2bf(f0.w);
            pk[4] = (short)f2bf(f1.x); pk[5] = (short)f2bf(f1.y);
            pk[6] = (short)f2bf(f1.z); pk[7] = (short)f2bf(f1.w);
            *(short8*)((char*)Als + chunk * 16) = pk;
        }
        // B: 2048 chunks via global_load_lds (swizzled global source)
        #pragma unroll
        for (int i = 0; i < 4; ++i) {
            int c0 = i * 512 + w * 64;
            int c  = c0 + lane;
            int row = c >> 3, sl = c & 7;
            const ushort* gp = Bt + (size_t)(bcol + row) * 512 + kt * 64 + ((sl ^ (row & 7)) * 8);
            __builtin_amdgcn_global_load_lds((const GLOBAL_AS void*)gp,
                                             (LDS_AS void*)(Bls + c0 * 8), 16, 0, 0);
        }
        __syncthreads();
        const char* AlsB = (const char*)Als;
        const char* BlsB = (const char*)Bls;
        #pragma unroll
        for (int kh = 0; kh < 2; ++kh) {
            int ks = kh * 4 + l4;
            short8 a[4], b[4];
            #pragma unroll
            for (int m = 0; m < 4; ++m) {
                int row = wm * 64 + m * 16 + l15;
                a[m] = *(const short8*)(AlsB + (row * 8 + (ks ^ (row & 7))) * 16);
            }
            #pragma unroll
            for (int n = 0; n < 4; ++n) {
                int rowb = wn * 64 + n * 16 + l15;
                b[n] = *(const short8*)(BlsB + (rowb * 8 + (ks ^ (rowb & 7))) * 16);
            }
            #pragma unroll
            for (int m = 0; m < 4; ++m)
                #pragma unroll
                for (int n = 0; n < 4; ++n)
                    acc[m][n] = __builtin_amdgcn_mfma_f32_16x16x32_bf16(a[m], b[n], acc[m][n], 0, 0, 0);
        }
    }
    // fused epilogue: tanh + vsum-weighted row reduction
    float part[4][4] = {};
    #pragma unroll
    for (int m = 0; m < 4; ++m) {
        int yb = (brow >> 4) + wm * 4 + m;
        #pragma unroll
        for (int n = 0; n < 4; ++n) {
            int gc = bcol + wn * 64 + n * 16 + l15;
            float yv = Y[(size_t)yb * 512 + gc];
            float vs = vsum[gc];
            #pragma unroll
            for (int r = 0; r < 4; ++r)
                part[m][r] += fast_tanh(acc[m][n][r] + yv) * vs;
        }
    }
    #pragma unroll
    for (int m = 0; m < 4; ++m)
        #pragma unroll
        for (int r = 0; r < 4; ++r) {
            float v = part[m][r];
            v += __shfl_xor(v, 1); v += __shfl_xor(v, 2);
            v += __shfl_xor(v, 4); v += __shfl_xor(v, 8);
            if (l15 == 0)
                sred[wn][wm * 64 + m * 16 + l4 * 4 + r] = v;
        }
    __syncthreads();
    if (tid < 128)
        spart[(size_t)blockIdx.x * (BB * LL) + brow + tid] =
            sred[0][tid] + sred[1][tid] + sred[2][tid] + sred[3][tid];
}

// ---------------------------------------------------------------------------
// softmax_d3: one block per batch (128 thr, float4 lanes). Reduces spart,
// softmax over L=16, d = a @ AS, writes o_d + A7 right half, and streams
// the shifted o_ns rows 0..14 in the same pass.
// ---------------------------------------------------------------------------
__global__ __launch_bounds__(128) void softmax_d3(
    const float* __restrict__ spart, const float* __restrict__ ASf,
    float* __restrict__ o_ns, float* __restrict__ o_d, ushort* __restrict__ A7) {
    const int b = blockIdx.x, tid = threadIdx.x;
    __shared__ float s_l[LL];
    if (tid < LL)
        s_l[tid] = spart[(size_t)b * LL + tid] + spart[(size_t)BB * LL + b * LL + tid];
    __syncthreads();
    float mx = -1e30f;
    #pragma unroll
    for (int l = 0; l < LL; ++l) mx = fmaxf(mx, s_l[l]);
    float wgt[LL]; float sum = 0.f;
    #pragma unroll
    for (int l = 0; l < LL; ++l) { wgt[l] = __expf(s_l[l] - mx); sum += wgt[l]; }
    const float inv = 1.f / sum;
    const int c = tid * 4;
    float d0 = 0.f, d1 = 0.f, d2 = 0.f, d3 = 0.f;
    #pragma unroll
    for (int l = 0; l < LL; ++l) {
        float4 v = *(const float4*)(ASf + ((size_t)b * LL + l) * 512 + c);
        if (l >= 1)
            *(float4*)(o_ns + ((size_t)b * LL + l - 1) * 512 + c) = v;
        d0 += wgt[l] * v.x; d1 += wgt[l] * v.y;
        d2 += wgt[l] * v.z; d3 += wgt[l] * v.w;
    }
    d0 *= inv; d1 *= inv; d2 *= inv; d3 *= inv;
    float4 dv; dv.x = d0; dv.y = d1; dv.z = d2; dv.w = d3;
    *(float4*)(o_d + (size_t)b * 512 + c) = dv;
    ushort4 uv; uv.x = f2bf(d0); uv.y = f2bf(d1); uv.z = f2bf(d2); uv.w = f2bf(d3);
    *(ushort4*)(A7 + (size_t)b * 1024 + 512 + c) = uv;
}

// ---------------------------------------------------------------------------
// Merged weight transpose+cvt: all 5 weight matrices in one launch.
// ---------------------------------------------------------------------------
struct TrJob { const float* srcA; const float* srcB; int K0; ushort* dst; int N; int K; };
struct TrJobs { TrJob j[5]; };

__global__ void tr_cvt_all(TrJobs jobs) {
    TrJob jb = jobs.j[blockIdx.z];
    int bn = blockIdx.x, bk = blockIdx.y;
    if (bn * 32 >= jb.N || bk * 32 >= jb.K) return;
    __shared__ float tile[32][33];
    int tx = threadIdx.x, ty = threadIdx.y;  // 32 x 8
    #pragma unroll
    for (int j = 0; j < 4; ++j) {
        int k = bk * 32 + ty + j * 8;
        const float* s = (k < jb.K0) ? (jb.srcA + (size_t)k * jb.N)
                                     : (jb.srcB + (size_t)(k - jb.K0) * jb.N);
        tile[ty + j * 8][tx] = s[bn * 32 + tx];
    }
    __syncthreads();
    #pragma unroll
    for (int j = 0; j < 4; ++j) {
        int n = bn * 32 + ty + j * 8;
        jb.dst[(size_t)n * jb.K + bk * 32 + tx] = f2bf(tile[tx][ty + j * 8]);
    }
}

// Merged activation cvt (inputs/attns/cell_h -> bf16 halves of A1/A2)
struct CvJobs { const float* src[3]; ushort* dst[3]; };
__global__ void cvt_all(CvJobs jobs) {
    const float* src = jobs.src[blockIdx.y];
    ushort* dst = jobs.dst[blockIdx.y];
    int idx = blockIdx.x * 256 + threadIdx.x;
    int i4 = idx & 127, row = idx >> 7;
    float4 v = *(const float4*)(src + (size_t)row * 512 + i4 * 4);
    ushort4 o; o.x = f2bf(v.x); o.y = f2bf(v.y); o.z = f2bf(v.z); o.w = f2bf(v.w);
    *(ushort4*)(dst + (size_t)row * 1024 + i4 * 4) = o;
}

__global__ void lstm_ew(const float4* __restrict__ g4, const float4* __restrict__ cc4,
                        float4* __restrict__ c4, float4* __restrict__ h4,
                        ushort* __restrict__ A4, ushort* __restrict__ A7) {
    int idx = blockIdx.x * 256 + threadIdx.x;   // BB*128
    int b = idx >> 7, q = idx & 127;
    const float4* g = g4 + (size_t)b * 512;
    float4 gi = g[q], gf = g[q + 128], gg = g[q + 256], go = g[q + 384];
    float4 cc = cc4[idx];
    float4 c, h;
    #pragma unroll
    for (int j = 0; j < 4; ++j) {
        float fi = ((const float*)&gi)[j], ff = ((const float*)&gf)[j];
        float fg = ((const float*)&gg)[j], fo = ((const float*)&go)[j];
        float si = 1.f / (1.f + __expf(-fi));
        float sf = 1.f / (1.f + __expf(-ff));
        float so = 1.f / (1.f + __expf(-fo));
        float cv = sf * ((const float*)&cc)[j] + si * tanhf(fg);
        ((float*)&c)[j] = cv;
        ((float*)&h)[j] = so * tanhf(cv);
    }
    c4[idx] = c; h4[idx] = h;
    ushort4 uc, uh;
    uc.x = f2bf(c.x); uc.y = f2bf(c.y); uc.z = f2bf(c.z); uc.w = f2bf(c.w);
    uh.x = f2bf(h.x); uh.y = f2bf(h.y); uh.z = f2bf(h.z); uh.w = f2bf(h.w);
    *(ushort4*)(A4 + (size_t)b * 1024 + q * 4) = uc;
    *(ushort4*)(A4 + (size_t)b * 1024 + 512 + q * 4) = uh;
    *(ushort4*)(A7 + (size_t)b * 1024 + q * 4) = uh;
}

__global__ void vsum_k(const float* __restrict__ Vm, float* __restrict__ out) {
    __shared__ float red[8][32];
    int tc = threadIdx.x & 31, ts = threadIdx.x >> 5;
    int v = blockIdx.x * 32 + tc;
    float acc = 0.f;
    for (int s = ts; s < SS; s += 8) acc += Vm[(size_t)s * VV + v];
    red[ts][tc] = acc;
    __syncthreads();
    if (ts == 0) {
        float t = 0.f;
        #pragma unroll
        for (int j = 0; j < 8; ++j) t += red[j][tc];
        out[v] = t;
    }
}

extern "C" void kernel_launch(void* const* d_in, const int* in_sizes, int n_in,
                              void* d_out, int out_size, void* d_ws, size_t ws_size,
                              hipStream_t stream) {
    const float* inputs      = (const float*)d_in[0];
    const float* cell_c      = (const float*)d_in[1];
    const float* cell_h      = (const float*)d_in[2];
    const float* attns       = (const float*)d_in[3];
    const float* attn_states = (const float*)d_in[4];
    const float* W1          = (const float*)d_in[5];
    const float* b1          = (const float*)d_in[6];
    const float* Wx          = (const float*)d_in[7];
    const float* Wh          = (const float*)d_in[8];
    const float* b_lstm      = (const float*)d_in[9];
    const float* W3          = (const float*)d_in[10];
    const float* b3          = (const float*)d_in[11];
    const float* kmat        = (const float*)d_in[12];
    const float* vmat        = (const float*)d_in[13];
    const float* W2          = (const float*)d_in[14];
    const float* b2          = (const float*)d_in[15];

    float* o_out = (float*)d_out;
    float* o_c   = o_out + (size_t)BB * HH;
    float* o_h   = o_c   + (size_t)BB * HH;
    float* o_d   = o_h   + (size_t)BB * HH;
    float* o_ns  = o_d   + (size_t)BB * SS;

    float* ws_gates = (float*)d_ws;                          // B*4H
    float* ws_y     = ws_gates + (size_t)BB * 4 * HH;        // B*V
    float* ws_vsum  = ws_y + (size_t)BB * VV;                // V
    float* ws_spart = ws_vsum + VV;                          // 2*B*L
    ushort* A1    = (ushort*)(ws_spart + (size_t)2 * BB * LL);
    ushort* A2    = A1 + (size_t)BB * 1024;
    ushort* A4    = A2 + (size_t)BB * 1024;
    ushort* A7    = A4 + (size_t)BB * 1024;
    ushort* W1t   = A7 + (size_t)BB * 1024;                  // [512][1024]
    ushort* WxWht = W1t + (size_t)512 * 1024;                // [2048][1024]
    ushort* W3t   = WxWht + (size_t)2048 * 1024;             // [512][1024]
    ushort* W2t   = W3t + (size_t)512 * 1024;                // [512][1024]
    ushort* kTt   = W2t + (size_t)512 * 1024;                // [512][512]

    TrJobs tj;
    tj.j[0] = {W1, W1, 1024, W1t, 512, 1024};
    tj.j[1] = {Wx, Wh, 512, WxWht, 2048, 1024};
    tj.j[2] = {W3, W3, 1024, W3t, 512, 1024};
    tj.j[3] = {W2, W2, 1024, W2t, 512, 1024};
    tj.j[4] = {kmat, kmat, 512, kTt, 512, 512};
    tr_cvt_all<<<dim3(64, 32, 5), dim3(32, 8), 0, stream>>>(tj);
    CvJobs cj;
    cj.src[0] = inputs; cj.dst[0] = A1;
    cj.src[1] = attns;  cj.dst[1] = A1 + 512;
    cj.src[2] = cell_h; cj.dst[2] = A2 + 512;
    cvt_all<<<dim3(BB * 128 / 256, 3), 256, 0, stream>>>(cj);
    vsum_k<<<16, 256, 0, stream>>>(vmat, ws_vsum);

    // 1. x = [inputs|attns] @ W1 + b1 -> bf16 into A2 left half
    gemm_mfma<1, 1><<<dim3(512 / 32, BB / 128), 256, 0, stream>>>(
        A1, W1t, b1, A2, nullptr, 1024, BB, 512, 1024);
    // 2. gates = [x|cell_h] @ [Wx;Wh] + b_lstm
    gemm_mfma<0, 4><<<dim3(2048 / 128, BB / 128), 256, 0, stream>>>(
        A2, WxWht, b_lstm, ws_gates, nullptr, 2048, BB, 2048, 1024);
    // 3. LSTM elementwise
    lstm_ew<<<BB * 128 / 256, 256, 0, stream>>>(
        (const float4*)ws_gates, (const float4*)cell_c,
        (float4*)o_c, (float4*)o_h, A4, A7);
    // 4. y = [c|h] @ W3 + b3
    gemm_mfma<0, 1><<<dim3(512 / 32, BB / 128), 256, 0, stream>>>(
        A4, W3t, b3, ws_y, nullptr, 512, BB, 512, 1024);
    // 5. score partials (streaming, BN=256, 8 waves)
    gemm_score<<<dim3(2, 512), 512, 0, stream>>>(
        attn_states, kTt, ws_y, ws_vsum, ws_spart);
    // 6. reduce + softmax + d + o_ns rows 0..14 (one streaming pass)
    softmax_d3<<<BB, 128, 0, stream>>>(
        ws_spart, attn_states, o_ns, o_d, A7);
    // 7+8b. output = [h|d] @ W2 + b2 (also writes o_ns row 15)
    gemm_mfma<2, 1><<<dim3(512 / 32, BB / 128), 256, 0, stream>>>(
        A7, W2t, b2, o_out, o_ns, 512, BB, 512, 1024);
}

// Round 9
// 235.443 us; speedup vs baseline: 1.4583x; 1.0526x over previous
//
#include <hip/hip_runtime.h>
#include <hip/hip_bf16.h>
#include <math.h>

#define BB 4096
#define LL 16
#define SS 512
#define VV 512
#define II 512
#define HH 512

typedef __attribute__((ext_vector_type(4))) float f32x4;
typedef __attribute__((ext_vector_type(8))) short short8;

#define GLOBAL_AS __attribute__((address_space(1)))
#define LDS_AS __attribute__((address_space(3)))

__device__ __forceinline__ unsigned short f2bf(float f) {
    union { float f; unsigned u; } c; c.f = f;
    unsigned u = c.u + 0x7FFFu + ((c.u >> 16) & 1u);
    return (unsigned short)(u >> 16);
}
__device__ __forceinline__ float bf2f(unsigned short u) {
    union { unsigned u; float f; } c; c.u = ((unsigned)u) << 16;
    return c.f;
}
__device__ __forceinline__ float fast_tanh(float x) {
    return 1.f - 2.f / (__expf(2.f * x) + 1.f);
}

// ---------------------------------------------------------------------------
// MFMA GEMM, m97-style: BM=128, BN=NF*32, BK=64. 256 threads = 4 waves (2x2).
// MODE 0: float out. MODE 1: bf16 out. MODE 2: float out + o_ns row-15 copy.
// ---------------------------------------------------------------------------
template<int MODE, int NF>
__global__ __launch_bounds__(256) void gemm_mfma(
    const ushort* __restrict__ A, const ushort* __restrict__ Bt,
    const float* __restrict__ bias, void* __restrict__ C, float* __restrict__ C2,
    int ldc, int M, int N, int K) {
    constexpr int BN = NF * 32;
    __shared__ ushort Als[128 * 64];
    __shared__ ushort Bls[BN * 64];
    const int tid  = threadIdx.x;
    const int lane = tid & 63;
    const int w    = tid >> 6;
    const int wm   = w >> 1, wn = w & 1;
    const int brow = blockIdx.y * 128;
    const int bcol = blockIdx.x * BN;
    f32x4 acc[4][NF] = {};
    const int nkt = K >> 6;
    for (int kt = 0; kt < nkt; ++kt) {
        __syncthreads();
        #pragma unroll
        for (int i = 0; i < 4; ++i) {           // A: 1024 chunks of 16B
            int c0 = i * 256 + w * 64;
            int c  = c0 + lane;
            int row = c >> 3, sl = c & 7;
            const ushort* gp = A + (size_t)(brow + row) * K + kt * 64 + ((sl ^ (row & 7)) * 8);
            __builtin_amdgcn_global_load_lds((const GLOBAL_AS void*)gp,
                                             (LDS_AS void*)(Als + c0 * 8), 16, 0, 0);
        }
        #pragma unroll
        for (int i = 0; i < NF; ++i) {          // B: BN*8 chunks
            int c0 = i * 256 + w * 64;
            int c  = c0 + lane;
            int row = c >> 3, sl = c & 7;
            const ushort* gp = Bt + (size_t)(bcol + row) * K + kt * 64 + ((sl ^ (row & 7)) * 8);
            __builtin_amdgcn_global_load_lds((const GLOBAL_AS void*)gp,
                                             (LDS_AS void*)(Bls + c0 * 8), 16, 0, 0);
        }
        __syncthreads();
        const char* AlsB = (const char*)Als;
        const char* BlsB = (const char*)Bls;
        #pragma unroll
        for (int kh = 0; kh < 2; ++kh) {
            int ks = kh * 4 + (lane >> 4);
            short8 a[4], b[NF];
            #pragma unroll
            for (int m = 0; m < 4; ++m) {
                int row = wm * 64 + m * 16 + (lane & 15);
                a[m] = *(const short8*)(AlsB + (row * 8 + (ks ^ (row & 7))) * 16);
            }
            #pragma unroll
            for (int n = 0; n < NF; ++n) {
                int row = wn * (NF * 16) + n * 16 + (lane & 15);
                b[n] = *(const short8*)(BlsB + (row * 8 + (ks ^ (row & 7))) * 16);
            }
            #pragma unroll
            for (int m = 0; m < 4; ++m)
                #pragma unroll
                for (int n = 0; n < NF; ++n)
                    acc[m][n] = __builtin_amdgcn_mfma_f32_16x16x32_bf16(a[m], b[n], acc[m][n], 0, 0, 0);
        }
    }
    #pragma unroll
    for (int m = 0; m < 4; ++m)
        #pragma unroll
        for (int n = 0; n < NF; ++n)
            #pragma unroll
            for (int r = 0; r < 4; ++r) {
                int gm = brow + wm * 64 + m * 16 + (lane >> 4) * 4 + r;
                int gc = bcol + wn * (NF * 16) + n * 16 + (lane & 15);
                float v = acc[m][n][r] + bias[gc];
                if (MODE == 1) ((ushort*)C)[(size_t)gm * ldc + gc] = f2bf(v);
                else           ((float*)C)[(size_t)gm * ldc + gc] = v;
                if (MODE == 2) C2[((size_t)gm * 16 + 15) * 512 + gc] = v;
            }
}

// ---------------------------------------------------------------------------
// score_all: fully fused score GEMM + softmax + d + o_ns shift.
// BM=64 (4 batches), BN=512 (ALL cols -> s block-local), 512 thr = 8 waves.
// Wave w owns col-slice w*64..+63 of all 64 rows; acc[4][4].
// Phase 1: R8-verified streaming kt-loop (A reg-staged fp32->bf16 swizzled
//          LDS, B via global_load_lds). LDS = 8KB A + 64KB B -> 2 blocks/CU.
// Phase 2: block-local s reduce + softmax (L=16).
// Phase 3: d = a@AS + o_ns shift, re-reading block's A tile (L2/L3-hot).
// ---------------------------------------------------------------------------
__global__ __launch_bounds__(512, 4) void score_all(
    const float* __restrict__ ASf, const ushort* __restrict__ Bt,
    const float* __restrict__ Y, const float* __restrict__ vsum,
    float* __restrict__ o_ns, float* __restrict__ o_d, ushort* __restrict__ A7) {
    __shared__ ushort Als[64 * 64];     // 8 KB
    __shared__ ushort Bls[512 * 64];    // 64 KB
    __shared__ float sred[8][64];
    __shared__ float s_lds[64];
    const int tid  = threadIdx.x;
    const int lane = tid & 63;
    const int w    = tid >> 6;          // 0..7
    const int l15  = lane & 15, l4 = lane >> 4;
    const int brow = blockIdx.x * 64;
    const int bg0  = brow >> 4;         // 4 batches per block
    f32x4 acc[4][4] = {};
    for (int kt = 0; kt < 8; ++kt) {
        __syncthreads();
        // A: 512 16B-chunks, 1/thread, fp32->bf16 cvt, swizzled write
        {
            int chunk = tid;
            int row = chunk >> 3, slot = chunk & 7;
            int gslot = slot ^ (row & 7);
            const float* gp = ASf + (size_t)(brow + row) * 512 + kt * 64 + gslot * 8;
            float4 f0 = *(const float4*)gp;
            float4 f1 = *(const float4*)(gp + 4);
            short8 pk;
            pk[0] = (short)f2bf(f0.x); pk[1] = (short)f2bf(f0.y);
            pk[2] = (short)f2bf(f0.z); pk[3] = (short)f2bf(f0.w);
            pk[4] = (short)f2bf(f1.x); pk[5] = (short)f2bf(f1.y);
            pk[6] = (short)f2bf(f1.z); pk[7] = (short)f2bf(f1.w);
            *(short8*)((char*)Als + chunk * 16) = pk;
        }
        // B: 4096 chunks via global_load_lds (swizzled global source)
        #pragma unroll
        for (int i = 0; i < 8; ++i) {
            int c0 = i * 512 + w * 64;
            int c  = c0 + lane;
            int row = c >> 3, sl = c & 7;
            const ushort* gp = Bt + (size_t)row * 512 + kt * 64 + ((sl ^ (row & 7)) * 8);
            __builtin_amdgcn_global_load_lds((const GLOBAL_AS void*)gp,
                                             (LDS_AS void*)(Bls + c0 * 8), 16, 0, 0);
        }
        __syncthreads();
        const char* AlsB = (const char*)Als;
        const char* BlsB = (const char*)Bls;
        #pragma unroll
        for (int kh = 0; kh < 2; ++kh) {
            int ks = kh * 4 + l4;
            short8 a[4], b[4];
            #pragma unroll
            for (int m = 0; m < 4; ++m) {
                int row = m * 16 + l15;
                a[m] = *(const short8*)(AlsB + (row * 8 + (ks ^ (row & 7))) * 16);
            }
            #pragma unroll
            for (int n = 0; n < 4; ++n) {
                int rowb = w * 64 + n * 16 + l15;
                b[n] = *(const short8*)(BlsB + (rowb * 8 + (ks ^ (rowb & 7))) * 16);
            }
            #pragma unroll
            for (int m = 0; m < 4; ++m)
                #pragma unroll
                for (int n = 0; n < 4; ++n)
                    acc[m][n] = __builtin_amdgcn_mfma_f32_16x16x32_bf16(a[m], b[n], acc[m][n], 0, 0, 0);
        }
    }
    // ---- Phase 2: tanh*vsum epilogue + block-local s reduce ----
    float part[4][4] = {};
    #pragma unroll
    for (int m = 0; m < 4; ++m) {
        int yb = bg0 + m;
        #pragma unroll
        for (int n = 0; n < 4; ++n) {
            int gc = w * 64 + n * 16 + l15;
            float yv = Y[(size_t)yb * 512 + gc];
            float vs = vsum[gc];
            #pragma unroll
            for (int r = 0; r < 4; ++r)
                part[m][r] += fast_tanh(acc[m][n][r] + yv) * vs;
        }
    }
    #pragma unroll
    for (int m = 0; m < 4; ++m)
        #pragma unroll
        for (int r = 0; r < 4; ++r) {
            float v = part[m][r];
            v += __shfl_xor(v, 1); v += __shfl_xor(v, 2);
            v += __shfl_xor(v, 4); v += __shfl_xor(v, 8);
            if (l15 == 0) sred[w][m * 16 + l4 * 4 + r] = v;
        }
    __syncthreads();
    if (tid < 64) {
        float v = 0.f;
        #pragma unroll
        for (int q = 0; q < 8; ++q) v += sred[q][tid];
        s_lds[tid] = v;
    }
    __syncthreads();

    // ---- Phase 3: softmax + d + o_ns shift (re-read own tile, L2/L3-hot) ----
    {
        const int bat = w >> 1;             // local batch 0..3
        const int bg  = bg0 + bat;
        const int c   = (w & 1) * 256 + lane * 4;
        float mx = -1e30f;
        #pragma unroll
        for (int l = 0; l < LL; ++l) mx = fmaxf(mx, s_lds[bat * 16 + l]);
        float wgt[LL]; float sum = 0.f;
        #pragma unroll
        for (int l = 0; l < LL; ++l) { wgt[l] = __expf(s_lds[bat * 16 + l] - mx); sum += wgt[l]; }
        const float inv = 1.f / sum;
        float d0 = 0.f, d1 = 0.f, d2 = 0.f, d3 = 0.f;
        #pragma unroll
        for (int l = 0; l < LL; ++l) {
            float4 v = *(const float4*)(ASf + ((size_t)bg * 16 + l) * 512 + c);
            if (l >= 1)
                *(float4*)(o_ns + ((size_t)bg * 16 + l - 1) * 512 + c) = v;
            d0 += wgt[l] * v.x; d1 += wgt[l] * v.y;
            d2 += wgt[l] * v.z; d3 += wgt[l] * v.w;
        }
        d0 *= inv; d1 *= inv; d2 *= inv; d3 *= inv;
        float4 dv; dv.x = d0; dv.y = d1; dv.z = d2; dv.w = d3;
        *(float4*)(o_d + (size_t)bg * 512 + c) = dv;
        ushort4 uv; uv.x = f2bf(d0); uv.y = f2bf(d1); uv.z = f2bf(d2); uv.w = f2bf(d3);
        *(ushort4*)(A7 + (size_t)bg * 1024 + 512 + c) = uv;
    }
}

// ---------------------------------------------------------------------------
// Merged weight transpose+cvt: all 5 weight matrices in one launch.
// ---------------------------------------------------------------------------
struct TrJob { const float* srcA; const float* srcB; int K0; ushort* dst; int N; int K; };
struct TrJobs { TrJob j[5]; };

__global__ void tr_cvt_all(TrJobs jobs) {
    TrJob jb = jobs.j[blockIdx.z];
    int bn = blockIdx.x, bk = blockIdx.y;
    if (bn * 32 >= jb.N || bk * 32 >= jb.K) return;
    __shared__ float tile[32][33];
    int tx = threadIdx.x, ty = threadIdx.y;  // 32 x 8
    #pragma unroll
    for (int j = 0; j < 4; ++j) {
        int k = bk * 32 + ty + j * 8;
        const float* s = (k < jb.K0) ? (jb.srcA + (size_t)k * jb.N)
                                     : (jb.srcB + (size_t)(k - jb.K0) * jb.N);
        tile[ty + j * 8][tx] = s[bn * 32 + tx];
    }
    __syncthreads();
    #pragma unroll
    for (int j = 0; j < 4; ++j) {
        int n = bn * 32 + ty + j * 8;
        jb.dst[(size_t)n * jb.K + bk * 32 + tx] = f2bf(tile[tx][ty + j * 8]);
    }
}

// Merged activation cvt (inputs/attns/cell_h -> bf16 halves of A1/A2)
struct CvJobs { const float* src[3]; ushort* dst[3]; };
__global__ void cvt_all(CvJobs jobs) {
    const float* src = jobs.src[blockIdx.y];
    ushort* dst = jobs.dst[blockIdx.y];
    int idx = blockIdx.x * 256 + threadIdx.x;
    int i4 = idx & 127, row = idx >> 7;
    float4 v = *(const float4*)(src + (size_t)row * 512 + i4 * 4);
    ushort4 o; o.x = f2bf(v.x); o.y = f2bf(v.y); o.z = f2bf(v.z); o.w = f2bf(v.w);
    *(ushort4*)(dst + (size_t)row * 1024 + i4 * 4) = o;
}

__global__ void lstm_ew(const float4* __restrict__ g4, const float4* __restrict__ cc4,
                        float4* __restrict__ c4, float4* __restrict__ h4,
                        ushort* __restrict__ A4, ushort* __restrict__ A7) {
    int idx = blockIdx.x * 256 + threadIdx.x;   // BB*128
    int b = idx >> 7, q = idx & 127;
    const float4* g = g4 + (size_t)b * 512;
    float4 gi = g[q], gf = g[q + 128], gg = g[q + 256], go = g[q + 384];
    float4 cc = cc4[idx];
    float4 c, h;
    #pragma unroll
    for (int j = 0; j < 4; ++j) {
        float fi = ((const float*)&gi)[j], ff = ((const float*)&gf)[j];
        float fg = ((const float*)&gg)[j], fo = ((const float*)&go)[j];
        float si = 1.f / (1.f + __expf(-fi));
        float sf = 1.f / (1.f + __expf(-ff));
        float so = 1.f / (1.f + __expf(-fo));
        float cv = sf * ((const float*)&cc)[j] + si * tanhf(fg);
        ((float*)&c)[j] = cv;
        ((float*)&h)[j] = so * tanhf(cv);
    }
    c4[idx] = c; h4[idx] = h;
    ushort4 uc, uh;
    uc.x = f2bf(c.x); uc.y = f2bf(c.y); uc.z = f2bf(c.z); uc.w = f2bf(c.w);
    uh.x = f2bf(h.x); uh.y = f2bf(h.y); uh.z = f2bf(h.z); uh.w = f2bf(h.w);
    *(ushort4*)(A4 + (size_t)b * 1024 + q * 4) = uc;
    *(ushort4*)(A4 + (size_t)b * 1024 + 512 + q * 4) = uh;
    *(ushort4*)(A7 + (size_t)b * 1024 + q * 4) = uh;
}

__global__ void vsum_k(const float* __restrict__ Vm, float* __restrict__ out) {
    __shared__ float red[8][32];
    int tc = threadIdx.x & 31, ts = threadIdx.x >> 5;
    int v = blockIdx.x * 32 + tc;
    float acc = 0.f;
    for (int s = ts; s < SS; s += 8) acc += Vm[(size_t)s * VV + v];
    red[ts][tc] = acc;
    __syncthreads();
    if (ts == 0) {
        float t = 0.f;
        #pragma unroll
        for (int j = 0; j < 8; ++j) t += red[j][tc];
        out[v] = t;
    }
}

extern "C" void kernel_launch(void* const* d_in, const int* in_sizes, int n_in,
                              void* d_out, int out_size, void* d_ws, size_t ws_size,
                              hipStream_t stream) {
    const float* inputs      = (const float*)d_in[0];
    const float* cell_c      = (const float*)d_in[1];
    const float* cell_h      = (const float*)d_in[2];
    const float* attns       = (const float*)d_in[3];
    const float* attn_states = (const float*)d_in[4];
    const float* W1          = (const float*)d_in[5];
    const float* b1          = (const float*)d_in[6];
    const float* Wx          = (const float*)d_in[7];
    const float* Wh          = (const float*)d_in[8];
    const float* b_lstm      = (const float*)d_in[9];
    const float* W3          = (const float*)d_in[10];
    const float* b3          = (const float*)d_in[11];
    const float* kmat        = (const float*)d_in[12];
    const float* vmat        = (const float*)d_in[13];
    const float* W2          = (const float*)d_in[14];
    const float* b2          = (const float*)d_in[15];

    float* o_out = (float*)d_out;
    float* o_c   = o_out + (size_t)BB * HH;
    float* o_h   = o_c   + (size_t)BB * HH;
    float* o_d   = o_h   + (size_t)BB * HH;
    float* o_ns  = o_d   + (size_t)BB * SS;

    float* ws_gates = (float*)d_ws;                          // B*4H
    float* ws_y     = ws_gates + (size_t)BB * 4 * HH;        // B*V
    float* ws_vsum  = ws_y + (size_t)BB * VV;                // V
    ushort* A1    = (ushort*)(ws_vsum + VV);                 // [B][1024]
    ushort* A2    = A1 + (size_t)BB * 1024;
    ushort* A4    = A2 + (size_t)BB * 1024;
    ushort* A7    = A4 + (size_t)BB * 1024;
    ushort* W1t   = A7 + (size_t)BB * 1024;                  // [512][1024]
    ushort* WxWht = W1t + (size_t)512 * 1024;                // [2048][1024]
    ushort* W3t   = WxWht + (size_t)2048 * 1024;             // [512][1024]
    ushort* W2t   = W3t + (size_t)512 * 1024;                // [512][1024]
    ushort* kTt   = W2t + (size_t)512 * 1024;                // [512][512]

    TrJobs tj;
    tj.j[0] = {W1, W1, 1024, W1t, 512, 1024};
    tj.j[1] = {Wx, Wh, 512, WxWht, 2048, 1024};
    tj.j[2] = {W3, W3, 1024, W3t, 512, 1024};
    tj.j[3] = {W2, W2, 1024, W2t, 512, 1024};
    tj.j[4] = {kmat, kmat, 512, kTt, 512, 512};
    tr_cvt_all<<<dim3(64, 32, 5), dim3(32, 8), 0, stream>>>(tj);
    CvJobs cj;
    cj.src[0] = inputs; cj.dst[0] = A1;
    cj.src[1] = attns;  cj.dst[1] = A1 + 512;
    cj.src[2] = cell_h; cj.dst[2] = A2 + 512;
    cvt_all<<<dim3(BB * 128 / 256, 3), 256, 0, stream>>>(cj);
    vsum_k<<<16, 256, 0, stream>>>(vmat, ws_vsum);

    // 1. x = [inputs|attns] @ W1 + b1 -> bf16 into A2 left half
    gemm_mfma<1, 1><<<dim3(512 / 32, BB / 128), 256, 0, stream>>>(
        A1, W1t, b1, A2, nullptr, 1024, BB, 512, 1024);
    // 2. gates = [x|cell_h] @ [Wx;Wh] + b_lstm
    gemm_mfma<0, 4><<<dim3(2048 / 128, BB / 128), 256, 0, stream>>>(
        A2, WxWht, b_lstm, ws_gates, nullptr, 2048, BB, 2048, 1024);
    // 3. LSTM elementwise
    lstm_ew<<<BB * 128 / 256, 256, 0, stream>>>(
        (const float4*)ws_gates, (const float4*)cell_c,
        (float4*)o_c, (float4*)o_h, A4, A7);
    // 4. y = [c|h] @ W3 + b3
    gemm_mfma<0, 1><<<dim3(512 / 32, BB / 128), 256, 0, stream>>>(
        A4, W3t, b3, ws_y, nullptr, 512, BB, 512, 1024);
    // 5-6-8a. fully fused score + softmax + d + o_ns rows 0..14
    score_all<<<BB * LL / 64, 512, 0, stream>>>(
        attn_states, kTt, ws_y, ws_vsum, o_ns, o_d, A7);
    // 7+8b. output = [h|d] @ W2 + b2 (also writes o_ns row 15)
    gemm_mfma<2, 1><<<dim3(512 / 32, BB / 128), 256, 0, stream>>>(
        A7, W2t, b2, o_out, o_ns, 512, BB, 512, 1024);
}